// Round 8
// baseline (592.319 us; speedup 1.0000x reference)
//
#include <hip/hip_runtime.h>
#include <stdint.h>

#define NL    8192
#define NH    32768
#define FDIM  128
#define KSEL  32

// 16x16x16 morton grid over [-4,4)^3 (clamped), cell size 0.5
#define GLO   (-4.0f)
#define GINV  (2.0f)

typedef float f32x2 __attribute__((ext_vector_type(2)));
typedef float f32x4 __attribute__((ext_vector_type(4)));
typedef unsigned long long u64;

__device__ __forceinline__ int imin(int a, int b) { return a < b ? a : b; }
__device__ __forceinline__ int imax(int a, int b) { return a > b ? a : b; }
__device__ __forceinline__ u64 umin64(u64 a, u64 b) { return a < b ? a : b; }
__device__ __forceinline__ u64 umax64(u64 a, u64 b) { return a > b ? a : b; }

// ---------------------------------------------------------------------------
// Workspace layout (float offsets). Total 43272 floats = 173088 bytes.
// (identical to the round-5/6/7 VERIFIED build chain)
// ---------------------------------------------------------------------------
#define WS_P4    0       // 8192 * float4 (x,y,z, w=orig index bits)
#define WS_PBLO  32768   // 512 parents * 4 (u32-encoded, decoded to float)
#define WS_PBHI  34816   // 512 parents * 4
#define WS_OFF   36864   // u16[4097] CSR cell offsets
#define WS_POFF  38916   // u16[513]  parent offsets (written, unused by query)
#define WS_CNT   39176   // u32[4096] counts -> cursors
#define WS_FLOATS 43272
#define WS_BYTES  (WS_FLOATS * 4)

__device__ __forceinline__ uint32_t ordf(float f) {
    uint32_t u = __float_as_uint(f);
    return (u & 0x80000000u) ? ~u : (u | 0x80000000u);
}
__device__ __forceinline__ float iordf(uint32_t e) {
    return (e & 0x80000000u) ? __uint_as_float(e & 0x7FFFFFFFu)
                             : __uint_as_float(~e);
}
__device__ __forceinline__ int cellcoord(float p) {
    return imin(imax((int)floorf((p - GLO) * GINV), 0), 15);
}
__device__ __forceinline__ int mort12(int ix, int iy, int iz) {
    int m = 0;
#pragma unroll
    for (int b = 0; b < 4; ++b)
        m |= (((ix >> b) & 1) << (3 * b + 2)) |
             (((iy >> b) & 1) << (3 * b + 1)) |
             (((iz >> b) & 1) << (3 * b));
    return m;
}
__device__ __forceinline__ int deint4(int id, int sh) {   // bits at 3k+sh
    int v = 0;
#pragma unroll
    for (int b = 0; b < 4; ++b) v |= ((id >> (3 * b + sh)) & 1) << b;
    return v;
}
__device__ __forceinline__ float dist2f(f32x4 p, float qx, float qy, float qz) {
    const float dx = qx - p.x, dy = qy - p.y, dz = qz - p.z;
    return fmaf(dx, dx, fmaf(dy, dy, dz * dz));
}
// geometric dmin^2 to cell box (edge cells extended to infinity)
__device__ __forceinline__ float cell_dmin2(int cell, float qx, float qy, float qz) {
    const int cix = deint4(cell, 2), ciy = deint4(cell, 1), ciz = deint4(cell, 0);
    const float lx = (cix == 0)  ? -1e30f : GLO + 0.5f * cix;
    const float hx = (cix == 15) ?  1e30f : GLO + 0.5f * (cix + 1);
    const float ly = (ciy == 0)  ? -1e30f : GLO + 0.5f * ciy;
    const float hy = (ciy == 15) ?  1e30f : GLO + 0.5f * (ciy + 1);
    const float lz = (ciz == 0)  ? -1e30f : GLO + 0.5f * ciz;
    const float hz = (ciz == 15) ?  1e30f : GLO + 0.5f * (ciz + 1);
    const float gx = fmaxf(fmaxf(lx - qx, qx - hx), 0.0f);
    const float gy = fmaxf(fmaxf(ly - qy, qy - hy), 0.0f);
    const float gz = fmaxf(fmaxf(lz - qz, qz - hz), 0.0f);
    return fmaf(gx, gx, fmaf(gy, gy, gz * gz));
}

// ---------------------------------------------------------------------------
// Build kernels (VERIFIED rounds 5-7, unchanged)
// ---------------------------------------------------------------------------
__global__ __launch_bounds__(256)
void k_init(float* __restrict__ ws) {
    const int t = blockIdx.x * 256 + threadIdx.x;
    uint32_t* cnt = (uint32_t*)(ws + WS_CNT);
    uint32_t* elo = (uint32_t*)(ws + WS_PBLO);
    uint32_t* ehi = (uint32_t*)(ws + WS_PBHI);
    if (t < 4096) cnt[t] = 0u;
    if (t < 2048) { elo[t] = 0xFFFFFFFFu; ehi[t] = 0u; }
}

__global__ __launch_bounds__(256)
void k_count(const float* __restrict__ pos_l, float* __restrict__ ws) {
    const int e = blockIdx.x * 256 + threadIdx.x;
    if (e >= NL) return;
    const float px = pos_l[e * 3 + 0];
    const float py = pos_l[e * 3 + 1];
    const float pz = pos_l[e * 3 + 2];
    const int cell = mort12(cellcoord(px), cellcoord(py), cellcoord(pz));
    uint32_t* cnt = (uint32_t*)(ws + WS_CNT);
    uint32_t* elo = (uint32_t*)(ws + WS_PBLO);
    uint32_t* ehi = (uint32_t*)(ws + WS_PBHI);
    atomicAdd(&cnt[cell], 1u);
    const int par = cell >> 3;
    atomicMin(&elo[par * 4 + 0], ordf(px));
    atomicMin(&elo[par * 4 + 1], ordf(py));
    atomicMin(&elo[par * 4 + 2], ordf(pz));
    atomicMax(&ehi[par * 4 + 0], ordf(px));
    atomicMax(&ehi[par * 4 + 1], ordf(py));
    atomicMax(&ehi[par * 4 + 2], ordf(pz));
}

__global__ __launch_bounds__(1024)
void k_scan(float* __restrict__ ws) {
    __shared__ uint32_t s_c[1024];
    const int tid = threadIdx.x;
    uint32_t* cnt = (uint32_t*)(ws + WS_CNT);
    uint16_t* off16  = (uint16_t*)(ws + WS_OFF);
    uint16_t* poff16 = (uint16_t*)(ws + WS_POFF);

    const int base = tid * 4;
    const uint32_t v0 = cnt[base + 0], v1 = cnt[base + 1];
    const uint32_t v2 = cnt[base + 2], v3 = cnt[base + 3];
    const uint32_t s = v0 + v1 + v2 + v3;
    s_c[tid] = s;
    __syncthreads();
    for (int o = 1; o < 1024; o <<= 1) {
        const uint32_t t = (tid >= o) ? s_c[tid - o] : 0u;
        __syncthreads();
        s_c[tid] += t;
        __syncthreads();
    }
    uint32_t p = s_c[tid] - s;
    if ((tid & 1) == 0) poff16[tid >> 1] = (uint16_t)p;
    if (tid == 0)       poff16[512]      = (uint16_t)NL;
    off16[base + 0] = (uint16_t)p;           p += v0;
    off16[base + 1] = (uint16_t)p;           p += v1;
    off16[base + 2] = (uint16_t)p;           p += v2;
    off16[base + 3] = (uint16_t)p;
    if (tid == 1023) off16[4096] = (uint16_t)NL;
    cnt[base + 0] = 0u; cnt[base + 1] = 0u; cnt[base + 2] = 0u; cnt[base + 3] = 0u;

    if (tid < 512) {
        uint32_t* elo = (uint32_t*)(ws + WS_PBLO);
        uint32_t* ehi = (uint32_t*)(ws + WS_PBHI);
        float* flo = ws + WS_PBLO;
        float* fhi = ws + WS_PBHI;
        const bool empty = (ehi[tid * 4 + 0] == 0u);
#pragma unroll
        for (int d = 0; d < 3; ++d) {
            const float lo = empty ?  1e30f : iordf(elo[tid * 4 + d]);
            const float hi = empty ? -1e30f : iordf(ehi[tid * 4 + d]);
            flo[tid * 4 + d] = lo;
            fhi[tid * 4 + d] = hi;
        }
        flo[tid * 4 + 3] = 0.0f;
        fhi[tid * 4 + 3] = 0.0f;
    }
}

__global__ __launch_bounds__(256)
void k_scatter(const float* __restrict__ pos_l, float* __restrict__ ws) {
    const int e = blockIdx.x * 256 + threadIdx.x;
    if (e >= NL) return;
    const float px = pos_l[e * 3 + 0];
    const float py = pos_l[e * 3 + 1];
    const float pz = pos_l[e * 3 + 2];
    const int cell = mort12(cellcoord(px), cellcoord(py), cellcoord(pz));
    uint32_t* cnt = (uint32_t*)(ws + WS_CNT);
    const uint16_t* off16 = (const uint16_t*)(ws + WS_OFF);
    const uint32_t r = atomicAdd(&cnt[cell], 1u);
    const int pos = (int)off16[cell] + (int)r;
    f32x4* p4 = (f32x4*)(ws + WS_P4);
    f32x4 o; o.x = px; o.y = py; o.z = pz; o.w = __int_as_float(e);
    p4[pos] = o;
}

// ---------------------------------------------------------------------------
// Query kernel v4: one wave per query.
//   fast: tau0 (window) -> parent filter -> cell filter -> TAU-TIGHTEN
//         (lane-min sweep, E[M]~44 for any density) -> cell refilter ->
//         collect at taum (exact count) -> fp64 rerank
//   slow: (npar>128 | ncell>192 | M>128, rare) verified list-free streaming
// ---------------------------------------------------------------------------
#define QBLK  8
#define PLCAP 128
#define CCAP  192
#define MCAP  128
#define INFKEY 0xFFFFFFFFFFFFFFFFull

__global__ __launch_bounds__(512, 8)
void query_kernel(const float* __restrict__ x,
                  const float* __restrict__ pos_h,
                  const float* __restrict__ ws,
                  float* __restrict__ out)
{
    __shared__ float    s_blo[512][4];          // 8 KB parent content lo
    __shared__ float    s_bhi[512][4];          // 8 KB parent content hi
    __shared__ uint16_t s_off[4100];            // 8.2 KB cell CSR offsets
    __shared__ uint16_t s_pl[QBLK][PLCAP];      // 2 KB passing parents
    __shared__ uint16_t s_cell[QBLK][CCAP];     // 3 KB passing cells
    __shared__ uint16_t s_cand[QBLK][MCAP];     // 2 KB candidate slots
    __shared__ float    s_wd2[QBLK][KSEL];      // winner d2 -> norm weight
    __shared__ uint16_t s_widx[QBLK][KSEL];     // winner slot -> orig idx
    // total ~32.5 KB -> 4 blocks/CU (32 waves) at launch_bounds(512,8)

    const int tid  = threadIdx.x;
    const int lane = tid & 63;
    const int wid  = tid >> 6;
    const int gq   = blockIdx.x * QBLK + wid;

    for (int i = tid; i < 2048; i += 512) {
        ((float*)s_blo)[i] = ws[WS_PBLO + i];
        ((float*)s_bhi)[i] = ws[WS_PBHI + i];
    }
    {
        const uint16_t* og = (const uint16_t*)(ws + WS_OFF);
        for (int i = tid; i < 4097; i += 512) s_off[i] = og[i];
    }
    __syncthreads();

    const f32x4* p4 = (const f32x4*)(ws + WS_P4);
    const float qx = pos_h[(size_t)gq * 3 + 0];
    const float qy = pos_h[(size_t)gq * 3 + 1];
    const float qz = pos_h[(size_t)gq * 3 + 2];
    const unsigned long long lt = (1ull << lane) - 1ull;

    // ---- tau0 = 32nd smallest over 64 REAL points (morton window) ----
    const int qcell = mort12(cellcoord(qx), cellcoord(qy), cellcoord(qz));
    const int w0 = imin(imax((int)s_off[qcell] - 24, 0), NL - 64);
    float v = dist2f(p4[w0 + lane], qx, qy, qz);
#pragma unroll
    for (int k2 = 2; k2 <= 64; k2 <<= 1) {
#pragma unroll
        for (int jj = k2 >> 1; jj >= 1; jj >>= 1) {
            const float o     = __shfl_xor(v, jj);
            const bool  up    = ((lane & k2) == 0);
            const bool  lower = ((lane & jj) == 0);
            v = (lower == up) ? fminf(v, o) : fmaxf(v, o);
        }
    }
    const float tau0r = __shfl(v, 31);
    const float tau0m = tau0r * 1.00002f + 1e-6f;

    // ---- parent filter (exact content bounds), 8 parents/lane ----
    int npar = 0;
#pragma unroll
    for (int r = 0; r < 8; ++r) {
        const int c = r * 64 + lane;
        const float ddx = fmaxf(fmaxf(s_blo[c][0] - qx, qx - s_bhi[c][0]), 0.0f);
        const float ddy = fmaxf(fmaxf(s_blo[c][1] - qy, qy - s_bhi[c][1]), 0.0f);
        const float ddz = fmaxf(fmaxf(s_blo[c][2] - qz, qz - s_bhi[c][2]), 0.0f);
        const float dmin = fmaf(ddx, ddx, fmaf(ddy, ddy, ddz * ddz));
        const bool pass = (dmin <= tau0m);
        const unsigned long long m = __ballot(pass);
        if (pass) {
            const int pos = npar + (int)__popcll(m & lt);
            if (pos < PLCAP) s_pl[wid][pos] = (uint16_t)c;
        }
        npar += (int)__popcll(m);
    }

    bool slow = (npar > PLCAP);

    // ---- cell filter at tau0m: 8 parents/round, geometric child boxes ----
    int ncell = 0;
    if (!slow) {
        for (int pi = 0; pi < npar; pi += 8) {
            const int g   = pi + (lane >> 3);
            const int par = (g < npar) ? (int)s_pl[wid][g] : -1;
            const int cell = (par >= 0) ? (par * 8 + (lane & 7)) : 0;
            int n = 0;
            float dmc = 1e30f;
            if (par >= 0) {
                n = (int)s_off[cell + 1] - (int)s_off[cell];
                dmc = cell_dmin2(cell, qx, qy, qz);
            }
            const bool pass = (n > 0) && (dmc <= tau0m);
            const unsigned long long m = __ballot(pass);
            if (pass) {
                const int pos = ncell + (int)__popcll(m & lt);
                if (pos < CCAP) s_cell[wid][pos] = (uint16_t)cell;
            }
            ncell += (int)__popcll(m);
        }
        slow = (ncell > CCAP);
    }

    // ---- TAU-TIGHTEN: lane-min sweep over passing cells' points ----
    // tau1 = 32nd-of-64 lane minima: >=32 distinct real points have d<=tau1
    // => tau1 >= true r32 (valid). E[count<=tau1] ~ 44 for any density.
    float taum = 0.0f;
    if (!slow) {
        float rmin = INFINITY;
        for (int ci = 0; ci < ncell; ++ci) {
            const int cell = (int)s_cell[wid][ci];
            const int a = (int)s_off[cell];
            const int e = (int)s_off[cell + 1];
            for (int j = a + lane; j < e; j += 64)
                rmin = fminf(rmin, dist2f(p4[j], qx, qy, qz));
        }
        float vv = rmin;
#pragma unroll
        for (int k2 = 2; k2 <= 64; k2 <<= 1) {
#pragma unroll
            for (int jj = k2 >> 1; jj >= 1; jj >>= 1) {
                const float o     = __shfl_xor(vv, jj);
                const bool  up    = ((lane & k2) == 0);
                const bool  lower = ((lane & jj) == 0);
                vv = (lower == up) ? fminf(vv, o) : fmaxf(vv, o);
            }
        }
        const float tau1r = __shfl(vv, 31);
        taum = fminf(tau1r, tau0r) * 1.00002f + 1e-6f;   // <= tau0m

        // ---- refilter cells at taum (read-then-compact, in place) ----
        uint16_t rc0 = 0, rc1 = 0, rc2 = 0;
        bool rp0 = false, rp1 = false, rp2 = false;
        {
            const int i0 = lane, i1 = 64 + lane, i2 = 128 + lane;
            if (i0 < ncell) { rc0 = s_cell[wid][i0]; rp0 = (cell_dmin2(rc0, qx, qy, qz) <= taum); }
            if (i1 < ncell) { rc1 = s_cell[wid][i1]; rp1 = (cell_dmin2(rc1, qx, qy, qz) <= taum); }
            if (i2 < ncell) { rc2 = s_cell[wid][i2]; rp2 = (cell_dmin2(rc2, qx, qy, qz) <= taum); }
        }
        int nc2 = 0;
        {
            const unsigned long long m0 = __ballot(rp0);
            if (rp0) s_cell[wid][nc2 + (int)__popcll(m0 & lt)] = rc0;
            nc2 += (int)__popcll(m0);
            const unsigned long long m1 = __ballot(rp1);
            if (rp1) s_cell[wid][nc2 + (int)__popcll(m1 & lt)] = rc1;
            nc2 += (int)__popcll(m1);
            const unsigned long long m2 = __ballot(rp2);
            if (rp2) s_cell[wid][nc2 + (int)__popcll(m2 & lt)] = rc2;
            nc2 += (int)__popcll(m2);
        }
        ncell = nc2;
    }

    // ---- collect at taum (exact count; one sweep over refiltered cells) ----
    int M = 0;
    if (!slow) {
        for (int ci = 0; ci < ncell; ++ci) {
            const int cell = (int)s_cell[wid][ci];
            const int a = (int)s_off[cell];
            const int e = (int)s_off[cell + 1];
            for (int rr = a; rr < e; rr += 64) {
                const int j = rr + lane;
                bool hit = false;
                if (j < e) hit = (dist2f(p4[j], qx, qy, qz) <= taum);
                const unsigned long long m = __ballot(hit);
                if (hit) {
                    const int pp = M + (int)__popcll(m & lt);
                    if (pp < MCAP) s_cand[wid][pp] = (uint16_t)j;
                }
                M += (int)__popcll(m);
            }
        }
        slow = (M > MCAP);
        // M >= 32 guaranteed: the >=32 points with d<=tau1 lie in kept cells
    }

    // =================== FAST PATH: fp64 re-rank of <=128 ===================
    if (!slow) {
        const double axd = (double)qx, ayd = (double)qy, azd = (double)qz;
        const int i0 = (2 * lane     < M) ? (int)s_cand[wid][2 * lane]     : -1;
        const int i1 = (2 * lane + 1 < M) ? (int)s_cand[wid][2 * lane + 1] : -1;
        float f0 = INFINITY, f1 = INFINITY;
        if (i0 >= 0) {
            const f32x4 p = p4[i0];
            const double dx = (double)p.x - axd, dy = (double)p.y - ayd, dz = (double)p.z - azd;
            f0 = (float)(dx * dx + dy * dy + dz * dz);
        }
        if (i1 >= 0) {
            const f32x4 p = p4[i1];
            const double dx = (double)p.x - axd, dy = (double)p.y - ayd, dz = (double)p.z - azd;
            f1 = (float)(dx * dx + dy * dy + dz * dz);
        }
        int v0 = __float_as_int(f0);
        int v1 = __float_as_int(f1);
#pragma unroll
        for (int k2 = 2; k2 <= 128; k2 <<= 1) {
            const bool up = ((lane & (k2 >> 1)) == 0);
#pragma unroll
            for (int j = k2 >> 1; j >= 2; j >>= 1) {
                const int  xo    = j >> 1;
                const bool lower = ((lane & xo) == 0);
                const int o0 = __shfl_xor(v0, xo);
                const int o1 = __shfl_xor(v1, xo);
                v0 = (lower == up) ? imin(v0, o0) : imax(v0, o0);
                v1 = (lower == up) ? imin(v1, o1) : imax(v1, o1);
            }
            const int mn = imin(v0, v1), mx = imax(v0, v1);
            v0 = up ? mn : mx;
            v1 = up ? mx : mn;
        }
        const int tau32 = __shfl(v1, 15);   // rank-31 key (32nd smallest)

        const bool a0 = (i0 >= 0) && (__float_as_int(f0) <= tau32);
        const bool a1 = (i1 >= 0) && (__float_as_int(f1) <= tau32);
        const unsigned long long b0 = __ballot(a0);
        const unsigned long long b1 = __ballot(a1);
        const int cb = (int)__popcll(b0 & lt) + (int)__popcll(b1 & lt);
        const int p0 = cb;
        const int p1 = cb + (a0 ? 1 : 0);
        if (a0 && p0 < KSEL) { s_wd2[wid][p0] = f0; s_widx[wid][p0] = (uint16_t)i0; }
        if (a1 && p1 < KSEL) { s_wd2[wid][p1] = f1; s_widx[wid][p1] = (uint16_t)i1; }
    }

    // ============ SLOW PATH (rare): list-free streaming top-64 ============
    if (slow) {
        u64 L = INFKEY;
#pragma unroll 1
        for (int r = 0; r < 8; ++r) {
            const int c = r * 64 + lane;
            const float ddx = fmaxf(fmaxf(s_blo[c][0] - qx, qx - s_bhi[c][0]), 0.0f);
            const float ddy = fmaxf(fmaxf(s_blo[c][1] - qy, qy - s_bhi[c][1]), 0.0f);
            const float ddz = fmaxf(fmaxf(s_blo[c][2] - qz, qz - s_bhi[c][2]), 0.0f);
            const float dmin = fmaf(ddx, ddx, fmaf(ddy, ddy, ddz * ddz));
            unsigned long long pm = __ballot(dmin <= tau0m);
            while (pm) {
                const int pl = __ffsll(pm) - 1; pm &= pm - 1;
                const int par = r * 64 + pl;
                const int a = (int)s_off[par * 8];
                const int e = (int)s_off[par * 8 + 8];   // children contiguous
                for (int rr = a; rr < e; rr += 64) {
                    const int j = rr + lane;
                    u64 b = INFKEY;
                    if (j < e) {
                        const float d2 = dist2f(p4[j], qx, qy, qz);
                        b = (((u64)__float_as_uint(d2)) << 16) | (u64)j;
                    }
                    const u64 worst = __shfl(L, 63);
                    if (!__any(b < worst)) continue;
#pragma unroll
                    for (int k2 = 2; k2 <= 64; k2 <<= 1) {
#pragma unroll
                        for (int jj = k2 >> 1; jj >= 1; jj >>= 1) {
                            const u64  o     = __shfl_xor(b, jj);
                            const bool up    = ((lane & k2) == 0);
                            const bool lower = ((lane & jj) == 0);
                            b = (lower == up) ? umin64(b, o) : umax64(b, o);
                        }
                    }
                    L = umin64(L, __shfl_xor(b, 63));
#pragma unroll
                    for (int jj = 32; jj >= 1; jj >>= 1) {
                        const u64 o = __shfl_xor(L, jj);
                        L = ((lane & jj) == 0) ? umin64(L, o) : umax64(L, o);
                    }
                }
            }
        }
        const double axd = (double)qx, ayd = (double)qy, azd = (double)qz;
        const bool valid = (L != INFKEY);
        const int  slot  = (int)(L & 0xFFFFull);
        float fd2 = INFINITY;
        if (valid) {
            const f32x4 p = p4[slot];
            const double dx = (double)p.x - axd;
            const double dy = (double)p.y - ayd;
            const double dz = (double)p.z - azd;
            fd2 = (float)(dx * dx + dy * dy + dz * dz);
        }
        u64 k2v = (((u64)__float_as_uint(fd2)) << 16)
                | (u64)(valid ? slot : 0xFFFF);
#pragma unroll
        for (int k2 = 2; k2 <= 64; k2 <<= 1) {
#pragma unroll
            for (int jj = k2 >> 1; jj >= 1; jj >>= 1) {
                const u64  o     = __shfl_xor(k2v, jj);
                const bool up    = ((lane & k2) == 0);
                const bool lower = ((lane & jj) == 0);
                k2v = (lower == up) ? umin64(k2v, o) : umax64(k2v, o);
            }
        }
        if (lane < KSEL) {
            s_wd2[wid][lane]  = __uint_as_float((uint32_t)(k2v >> 16));
            s_widx[wid][lane] = (uint16_t)(k2v & 0xFFFFull);
        }
    }

    // ---- common: weights (slot -> orig, normalize once) ----
    {
        float w = 0.0f;
        int orig = 0;
        if (lane < KSEL) {
            const int slot = (int)s_widx[wid][lane];
            orig = __float_as_int(p4[slot].w);
            w = __builtin_amdgcn_rcpf(fmaxf(s_wd2[wid][lane], 1e-16f));
        }
        float wsum = w;
#pragma unroll
        for (int d = 1; d < 32; d <<= 1) wsum += __shfl_xor(wsum, d);
        if (lane < KSEL) {
            s_wd2[wid][lane]  = w * __builtin_amdgcn_rcpf(wsum);
            s_widx[wid][lane] = (uint16_t)orig;
        }
    }

    // ---- feature gather + weighted average ----
    f32x2 acc = (f32x2){0.0f, 0.0f};
#pragma unroll 8
    for (int kk = 0; kk < KSEL; ++kk) {
        const float w    = s_wd2[wid][kk];
        const int   orig = (int)s_widx[wid][kk];
        const f32x2 r2 = *(const f32x2*)(x + (size_t)orig * FDIM + 2 * lane);
        acc.x = fmaf(w, r2.x, acc.x);
        acc.y = fmaf(w, r2.y, acc.y);
    }
    *(f32x2*)(out + (size_t)gq * FDIM + 2 * lane) = acc;
}

// ---------------------------------------------------------------------------
// Fallback: verified round-2 brute-force kernel (used if ws too small)
// ---------------------------------------------------------------------------
#define CHUNK  1024
#define NCHUNK (NL / CHUNK)
#define QPW    4
#define NWAVES 8
#define BLOCK  (NWAVES * 64)
#define QPB    (NWAVES * QPW)
#define BUFCAP 128

__device__ __forceinline__ f32x2 pk_fma_lo(f32x2 s0, f32x2 s1, f32x2 s2) {
    f32x2 d;
    asm("v_pk_fma_f32 %0, %1, %2, %3 op_sel:[0,0,0] op_sel_hi:[1,0,1]"
        : "=v"(d) : "v"(s0), "v"(s1), "v"(s2));
    return d;
}
__device__ __forceinline__ f32x2 pk_fma_hi(f32x2 s0, f32x2 s1, f32x2 s2) {
    f32x2 d;
    asm("v_pk_fma_f32 %0, %1, %2, %3 op_sel:[0,1,0] op_sel_hi:[1,1,1]"
        : "=v"(d) : "v"(s0), "v"(s1), "v"(s2));
    return d;
}

__global__ __launch_bounds__(BLOCK, 8)
void knn_interp_kernel(const float* __restrict__ x,
                       const float* __restrict__ pos_l,
                       const float* __restrict__ pos_h,
                       float* __restrict__ out)
{
    __shared__ f32x2    s_x[CHUNK/2], s_y[CHUNK/2], s_z[CHUNK/2], s_w[CHUNK/2];
    __shared__ uint16_t s_idx[QPB][BUFCAP];
    __shared__ uint32_t s_cnt[QPB];
    __shared__ float    s_wd2[QPB][KSEL];
    __shared__ uint16_t s_widx[QPB][KSEL];

    const int tid   = threadIdx.x;
    const int lane  = tid & 63;
    const int wid   = tid >> 6;
    const int qbase = blockIdx.x * QPB + wid * QPW;

    f32x2 hxq[QPW/2], hyq[QPW/2], hzq[QPW/2];
#pragma unroll
    for (int j = 0; j < QPW/2; ++j) {
        const float a0x = pos_h[(size_t)(qbase + 2*j    ) * 3 + 0];
        const float a0y = pos_h[(size_t)(qbase + 2*j    ) * 3 + 1];
        const float a0z = pos_h[(size_t)(qbase + 2*j    ) * 3 + 2];
        const float a1x = pos_h[(size_t)(qbase + 2*j + 1) * 3 + 0];
        const float a1y = pos_h[(size_t)(qbase + 2*j + 1) * 3 + 1];
        const float a1z = pos_h[(size_t)(qbase + 2*j + 1) * 3 + 2];
        hxq[j] = (f32x2){-2.0f * a0x, -2.0f * a1x};
        hyq[j] = (f32x2){-2.0f * a0y, -2.0f * a1y};
        hzq[j] = (f32x2){-2.0f * a0z, -2.0f * a1z};
    }
    f32x2 rminp[QPW];
#pragma unroll
    for (int q = 0; q < QPW; ++q) rminp[q] = (f32x2){INFINITY, INFINITY};

    for (int c = 0; c < NCHUNK; ++c) {
        __syncthreads();
        for (int i = tid; i < CHUNK/2; i += BLOCK) {
            const float* p = pos_l + (size_t)(c * CHUNK + 2 * i) * 3;
            const f32x2 A = *(const f32x2*)(p + 0);
            const f32x2 B = *(const f32x2*)(p + 2);
            const f32x2 C = *(const f32x2*)(p + 4);
            s_x[i] = (f32x2){A.x, B.y};
            s_y[i] = (f32x2){A.y, C.x};
            s_z[i] = (f32x2){B.x, C.y};
            s_w[i] = (f32x2){fmaf(A.x, A.x, fmaf(A.y, A.y, B.x * B.x)),
                             fmaf(B.y, B.y, fmaf(C.x, C.x, C.y * C.y))};
        }
        __syncthreads();
#pragma unroll
        for (int i = 0; i < CHUNK/128; ++i) {
            const int pi = i * 64 + lane;
            const f32x2 xp = s_x[pi], yp = s_y[pi], zp = s_z[pi], wp = s_w[pi];
#pragma unroll
            for (int j = 0; j < QPW/2; ++j) {
                f32x2 t0 = pk_fma_lo(xp, hxq[j], wp);
                t0 = pk_fma_lo(yp, hyq[j], t0);
                t0 = pk_fma_lo(zp, hzq[j], t0);
                rminp[2*j].x = fminf(rminp[2*j].x, t0.x);
                rminp[2*j].y = fminf(rminp[2*j].y, t0.y);
                f32x2 t1 = pk_fma_hi(xp, hxq[j], wp);
                t1 = pk_fma_hi(yp, hyq[j], t1);
                t1 = pk_fma_hi(zp, hzq[j], t1);
                rminp[2*j+1].x = fminf(rminp[2*j+1].x, t1.x);
                rminp[2*j+1].y = fminf(rminp[2*j+1].y, t1.y);
            }
        }
    }
    float tau_acc[QPW];
#pragma unroll
    for (int q = 0; q < QPW; ++q) {
        float v = fminf(rminp[q].x, rminp[q].y);
#pragma unroll
        for (int k = 2; k <= 64; k <<= 1) {
#pragma unroll
            for (int jj = k >> 1; jj >= 1; jj >>= 1) {
                const float o     = __shfl_xor(v, jj);
                const bool  up    = ((lane & k) == 0);
                const bool  lower = ((lane & jj) == 0);
                v = (lower == up) ? fminf(v, o) : fmaxf(v, o);
            }
        }
        tau_acc[q] = __shfl(v, 31) + 1e-4f;
    }
    if (tid < QPB) s_cnt[tid] = 0;
    for (int c = 0; c < NCHUNK; ++c) {
        __syncthreads();
        for (int i = tid; i < CHUNK/2; i += BLOCK) {
            const float* p = pos_l + (size_t)(c * CHUNK + 2 * i) * 3;
            const f32x2 A = *(const f32x2*)(p + 0);
            const f32x2 B = *(const f32x2*)(p + 2);
            const f32x2 C = *(const f32x2*)(p + 4);
            s_x[i] = (f32x2){A.x, B.y};
            s_y[i] = (f32x2){A.y, C.x};
            s_z[i] = (f32x2){B.x, C.y};
            s_w[i] = (f32x2){fmaf(A.x, A.x, fmaf(A.y, A.y, B.x * B.x)),
                             fmaf(B.y, B.y, fmaf(C.x, C.x, C.y * C.y))};
        }
        __syncthreads();
#pragma unroll 2
        for (int i = 0; i < CHUNK/128; ++i) {
            const int pi = i * 64 + lane;
            const f32x2 xp = s_x[pi], yp = s_y[pi], zp = s_z[pi], wp = s_w[pi];
            const int g0 = c * CHUNK + 2 * pi;
#pragma unroll
            for (int j = 0; j < QPW/2; ++j) {
                f32x2 t0 = pk_fma_lo(xp, hxq[j], wp);
                t0 = pk_fma_lo(yp, hyq[j], t0);
                t0 = pk_fma_lo(zp, hzq[j], t0);
                f32x2 t1 = pk_fma_hi(xp, hxq[j], wp);
                t1 = pk_fma_hi(yp, hyq[j], t1);
                t1 = pk_fma_hi(zp, hzq[j], t1);
                const int q0 = wid * QPW + 2*j;
                if (__any(fminf(t0.x, t0.y) <= tau_acc[2*j])) {
                    if (t0.x <= tau_acc[2*j]) {
                        const uint32_t p0 = atomicAdd(&s_cnt[q0], 1u);
                        if (p0 < BUFCAP) s_idx[q0][p0] = (uint16_t)g0;
                    }
                    if (t0.y <= tau_acc[2*j]) {
                        const uint32_t p0 = atomicAdd(&s_cnt[q0], 1u);
                        if (p0 < BUFCAP) s_idx[q0][p0] = (uint16_t)(g0 + 1);
                    }
                }
                if (__any(fminf(t1.x, t1.y) <= tau_acc[2*j+1])) {
                    if (t1.x <= tau_acc[2*j+1]) {
                        const uint32_t p0 = atomicAdd(&s_cnt[q0 + 1], 1u);
                        if (p0 < BUFCAP) s_idx[q0 + 1][p0] = (uint16_t)g0;
                    }
                    if (t1.y <= tau_acc[2*j+1]) {
                        const uint32_t p0 = atomicAdd(&s_cnt[q0 + 1], 1u);
                        if (p0 < BUFCAP) s_idx[q0 + 1][p0] = (uint16_t)(g0 + 1);
                    }
                }
            }
        }
    }
#pragma unroll 1
    for (int q = 0; q < QPW; ++q) {
        const int qq = wid * QPW + q;
        uint32_t M = s_cnt[qq];
        if (M > BUFCAP) M = BUFCAP;
        const double axd = (double)pos_h[(size_t)(qbase + q) * 3 + 0];
        const double ayd = (double)pos_h[(size_t)(qbase + q) * 3 + 1];
        const double azd = (double)pos_h[(size_t)(qbase + q) * 3 + 2];
        const int i0 = ((uint32_t)(2 * lane)     < M) ? (int)s_idx[qq][2 * lane]     : -1;
        const int i1 = ((uint32_t)(2 * lane + 1) < M) ? (int)s_idx[qq][2 * lane + 1] : -1;
        float f0 = INFINITY, f1 = INFINITY;
        if (i0 >= 0) {
            const double dx = (double)pos_l[i0 * 3 + 0] - axd;
            const double dy = (double)pos_l[i0 * 3 + 1] - ayd;
            const double dz = (double)pos_l[i0 * 3 + 2] - azd;
            f0 = (float)(dx * dx + dy * dy + dz * dz);
        }
        if (i1 >= 0) {
            const double dx = (double)pos_l[i1 * 3 + 0] - axd;
            const double dy = (double)pos_l[i1 * 3 + 1] - ayd;
            const double dz = (double)pos_l[i1 * 3 + 2] - azd;
            f1 = (float)(dx * dx + dy * dy + dz * dz);
        }
        int v0 = __float_as_int(f0);
        int v1 = __float_as_int(f1);
#pragma unroll
        for (int k = 2; k <= 128; k <<= 1) {
            const bool up = ((lane & (k >> 1)) == 0);
#pragma unroll
            for (int j = k >> 1; j >= 2; j >>= 1) {
                const int  xo    = j >> 1;
                const bool lower = ((lane & xo) == 0);
                const int o0 = __shfl_xor(v0, xo);
                const int o1 = __shfl_xor(v1, xo);
                v0 = (lower == up) ? imin(v0, o0) : imax(v0, o0);
                v1 = (lower == up) ? imin(v1, o1) : imax(v1, o1);
            }
            const int mn = imin(v0, v1), mx = imax(v0, v1);
            v0 = up ? mn : mx;
            v1 = up ? mx : mn;
        }
        const int tau32 = __shfl(v1, 15);
        const bool a0 = (i0 >= 0) && (__float_as_int(f0) <= tau32);
        const bool a1 = (i1 >= 0) && (__float_as_int(f1) <= tau32);
        const unsigned long long b0 = __ballot(a0);
        const unsigned long long b1 = __ballot(a1);
        const unsigned long long mb = (lane == 63) ? 0x7FFFFFFFFFFFFFFFull
                                                   : ((1ull << (lane + 1)) - 1ull) >> 1;
        const int base = __popcll(b0 & mb) + __popcll(b1 & mb);
        const int p0 = base;
        const int p1 = base + (a0 ? 1 : 0);
        if (a0 && p0 < KSEL) { s_wd2[qq][p0] = f0; s_widx[qq][p0] = (uint16_t)i0; }
        if (a1 && p1 < KSEL) { s_wd2[qq][p1] = f1; s_widx[qq][p1] = (uint16_t)i1; }
    }
#pragma unroll 1
    for (int q = 0; q < QPW; ++q) {
        const int qq = wid * QPW + q;
        const int gq = qbase + q;
        f32x2 acc = (f32x2){0.0f, 0.0f};
        float wsum = 0.0f;
#pragma unroll 8
        for (int kk = 0; kk < KSEL; ++kk) {
            const float d2 = s_wd2[qq][kk];
            const float w  = __builtin_amdgcn_rcpf(fmaxf(d2, 1e-16f));
            const int  idx = (int)s_widx[qq][kk];
            const f32x2 r2 = *(const f32x2*)(x + (size_t)idx * FDIM + 2 * lane);
            acc.x = fmaf(w, r2.x, acc.x);
            acc.y = fmaf(w, r2.y, acc.y);
            wsum += w;
        }
        const float invw = __builtin_amdgcn_rcpf(wsum);
        out[(size_t)gq * FDIM + 2 * lane]     = acc.x * invw;
        out[(size_t)gq * FDIM + 2 * lane + 1] = acc.y * invw;
    }
}

// ---------------------------------------------------------------------------
extern "C" void kernel_launch(void* const* d_in, const int* in_sizes, int n_in,
                              void* d_out, int out_size, void* d_ws, size_t ws_size,
                              hipStream_t stream) {
    const float* x     = (const float*)d_in[0];
    const float* pos_l = (const float*)d_in[1];
    const float* pos_h = (const float*)d_in[2];
    float* out = (float*)d_out;

    if (d_ws != nullptr && ws_size >= (size_t)WS_BYTES) {
        float* ws = (float*)d_ws;
        hipLaunchKernelGGL(k_init,    dim3(16), dim3(256),  0, stream, ws);
        hipLaunchKernelGGL(k_count,   dim3(32), dim3(256),  0, stream, pos_l, ws);
        hipLaunchKernelGGL(k_scan,    dim3(1),  dim3(1024), 0, stream, ws);
        hipLaunchKernelGGL(k_scatter, dim3(32), dim3(256),  0, stream, pos_l, ws);
        hipLaunchKernelGGL(query_kernel, dim3(NH / QBLK), dim3(512), 0, stream,
                           x, pos_h, ws, out);
    } else {
        hipLaunchKernelGGL(knn_interp_kernel, dim3(NH / QPB), dim3(BLOCK), 0, stream,
                           x, pos_l, pos_h, out);
    }
}

// Round 9
// 504.140 us; speedup vs baseline: 1.1749x; 1.1749x over previous
//
#include <hip/hip_runtime.h>
#include <stdint.h>

#define NL    8192
#define NH    32768
#define FDIM  128
#define KSEL  32

// 16x16x16 morton grid over [-4,4)^3 (clamped), cell size 0.5
#define GLO   (-4.0f)
#define GINV  (2.0f)

typedef float f32x2 __attribute__((ext_vector_type(2)));
typedef float f32x4 __attribute__((ext_vector_type(4)));
typedef unsigned long long u64;

__device__ __forceinline__ int imin(int a, int b) { return a < b ? a : b; }
__device__ __forceinline__ int imax(int a, int b) { return a > b ? a : b; }
__device__ __forceinline__ u64 umin64(u64 a, u64 b) { return a < b ? a : b; }
__device__ __forceinline__ u64 umax64(u64 a, u64 b) { return a > b ? a : b; }

// ---------------------------------------------------------------------------
// Workspace layout (float offsets). Total 65804 floats = 263216 bytes.
// Points/bounds/offsets identical to the VERIFIED round-5..8 build chain;
// adds a query morton-sort (qoff/qperm/qcnt).
// ---------------------------------------------------------------------------
#define WS_P4    0       // 8192 * float4 (x,y,z, w=orig index bits)
#define WS_PBLO  32768   // 512 parents * 4 (u32-encoded, decoded to float)
#define WS_PBHI  34816   // 512 parents * 4
#define WS_OFF   36864   // u16[4097] CSR cell offsets
#define WS_POFF  38916   // u16[513]  parent offsets (written, unused by query)
#define WS_CNT   39176   // u32[4096] counts -> cursors
#define WS_QOFF  43272   // u16[4097] query CSR offsets (2052 floats)
#define WS_QPERM 45324   // u16[32768] sorted->orig query ids (16384 floats)
#define WS_QCNT  61708   // u32[4096] query counts -> cursors
#define WS_FLOATS 65804
#define WS_BYTES  (WS_FLOATS * 4)

__device__ __forceinline__ uint32_t ordf(float f) {
    uint32_t u = __float_as_uint(f);
    return (u & 0x80000000u) ? ~u : (u | 0x80000000u);
}
__device__ __forceinline__ float iordf(uint32_t e) {
    return (e & 0x80000000u) ? __uint_as_float(e & 0x7FFFFFFFu)
                             : __uint_as_float(~e);
}
__device__ __forceinline__ int cellcoord(float p) {
    return imin(imax((int)floorf((p - GLO) * GINV), 0), 15);
}
__device__ __forceinline__ int mort12(int ix, int iy, int iz) {
    int m = 0;
#pragma unroll
    for (int b = 0; b < 4; ++b)
        m |= (((ix >> b) & 1) << (3 * b + 2)) |
             (((iy >> b) & 1) << (3 * b + 1)) |
             (((iz >> b) & 1) << (3 * b));
    return m;
}
__device__ __forceinline__ int deint4(int id, int sh) {   // bits at 3k+sh
    int v = 0;
#pragma unroll
    for (int b = 0; b < 4; ++b) v |= ((id >> (3 * b + sh)) & 1) << b;
    return v;
}
__device__ __forceinline__ float dist2f(f32x4 p, float qx, float qy, float qz) {
    const float dx = qx - p.x, dy = qy - p.y, dz = qz - p.z;
    return fmaf(dx, dx, fmaf(dy, dy, dz * dz));
}
// geometric dmin^2 to cell box (edge cells extended to infinity)
__device__ __forceinline__ float cell_dmin2(int cell, float qx, float qy, float qz) {
    const int cix = deint4(cell, 2), ciy = deint4(cell, 1), ciz = deint4(cell, 0);
    const float lx = (cix == 0)  ? -1e30f : GLO + 0.5f * cix;
    const float hx = (cix == 15) ?  1e30f : GLO + 0.5f * (cix + 1);
    const float ly = (ciy == 0)  ? -1e30f : GLO + 0.5f * ciy;
    const float hy = (ciy == 15) ?  1e30f : GLO + 0.5f * (ciy + 1);
    const float lz = (ciz == 0)  ? -1e30f : GLO + 0.5f * ciz;
    const float hz = (ciz == 15) ?  1e30f : GLO + 0.5f * (ciz + 1);
    const float gx = fmaxf(fmaxf(lx - qx, qx - hx), 0.0f);
    const float gy = fmaxf(fmaxf(ly - qy, qy - hy), 0.0f);
    const float gz = fmaxf(fmaxf(lz - qz, qz - hz), 0.0f);
    return fmaf(gx, gx, fmaf(gy, gy, gz * gz));
}

// ---------------------------------------------------------------------------
// Build kernels (VERIFIED rounds 5-8, unchanged)
// ---------------------------------------------------------------------------
__global__ __launch_bounds__(256)
void k_init(float* __restrict__ ws) {
    const int t = blockIdx.x * 256 + threadIdx.x;
    uint32_t* cnt = (uint32_t*)(ws + WS_CNT);
    uint32_t* elo = (uint32_t*)(ws + WS_PBLO);
    uint32_t* ehi = (uint32_t*)(ws + WS_PBHI);
    if (t < 4096) cnt[t] = 0u;
    if (t < 2048) { elo[t] = 0xFFFFFFFFu; ehi[t] = 0u; }
}

__global__ __launch_bounds__(256)
void k_count(const float* __restrict__ pos_l, float* __restrict__ ws) {
    const int e = blockIdx.x * 256 + threadIdx.x;
    if (e >= NL) return;
    const float px = pos_l[e * 3 + 0];
    const float py = pos_l[e * 3 + 1];
    const float pz = pos_l[e * 3 + 2];
    const int cell = mort12(cellcoord(px), cellcoord(py), cellcoord(pz));
    uint32_t* cnt = (uint32_t*)(ws + WS_CNT);
    uint32_t* elo = (uint32_t*)(ws + WS_PBLO);
    uint32_t* ehi = (uint32_t*)(ws + WS_PBHI);
    atomicAdd(&cnt[cell], 1u);
    const int par = cell >> 3;
    atomicMin(&elo[par * 4 + 0], ordf(px));
    atomicMin(&elo[par * 4 + 1], ordf(py));
    atomicMin(&elo[par * 4 + 2], ordf(pz));
    atomicMax(&ehi[par * 4 + 0], ordf(px));
    atomicMax(&ehi[par * 4 + 1], ordf(py));
    atomicMax(&ehi[par * 4 + 2], ordf(pz));
}

__global__ __launch_bounds__(1024)
void k_scan(float* __restrict__ ws) {
    __shared__ uint32_t s_c[1024];
    const int tid = threadIdx.x;
    uint32_t* cnt = (uint32_t*)(ws + WS_CNT);
    uint16_t* off16  = (uint16_t*)(ws + WS_OFF);
    uint16_t* poff16 = (uint16_t*)(ws + WS_POFF);

    const int base = tid * 4;
    const uint32_t v0 = cnt[base + 0], v1 = cnt[base + 1];
    const uint32_t v2 = cnt[base + 2], v3 = cnt[base + 3];
    const uint32_t s = v0 + v1 + v2 + v3;
    s_c[tid] = s;
    __syncthreads();
    for (int o = 1; o < 1024; o <<= 1) {
        const uint32_t t = (tid >= o) ? s_c[tid - o] : 0u;
        __syncthreads();
        s_c[tid] += t;
        __syncthreads();
    }
    uint32_t p = s_c[tid] - s;
    if ((tid & 1) == 0) poff16[tid >> 1] = (uint16_t)p;
    if (tid == 0)       poff16[512]      = (uint16_t)NL;
    off16[base + 0] = (uint16_t)p;           p += v0;
    off16[base + 1] = (uint16_t)p;           p += v1;
    off16[base + 2] = (uint16_t)p;           p += v2;
    off16[base + 3] = (uint16_t)p;
    if (tid == 1023) off16[4096] = (uint16_t)NL;
    cnt[base + 0] = 0u; cnt[base + 1] = 0u; cnt[base + 2] = 0u; cnt[base + 3] = 0u;

    if (tid < 512) {
        uint32_t* elo = (uint32_t*)(ws + WS_PBLO);
        uint32_t* ehi = (uint32_t*)(ws + WS_PBHI);
        float* flo = ws + WS_PBLO;
        float* fhi = ws + WS_PBHI;
        const bool empty = (ehi[tid * 4 + 0] == 0u);
#pragma unroll
        for (int d = 0; d < 3; ++d) {
            const float lo = empty ?  1e30f : iordf(elo[tid * 4 + d]);
            const float hi = empty ? -1e30f : iordf(ehi[tid * 4 + d]);
            flo[tid * 4 + d] = lo;
            fhi[tid * 4 + d] = hi;
        }
        flo[tid * 4 + 3] = 0.0f;
        fhi[tid * 4 + 3] = 0.0f;
    }
}

__global__ __launch_bounds__(256)
void k_scatter(const float* __restrict__ pos_l, float* __restrict__ ws) {
    const int e = blockIdx.x * 256 + threadIdx.x;
    if (e >= NL) return;
    const float px = pos_l[e * 3 + 0];
    const float py = pos_l[e * 3 + 1];
    const float pz = pos_l[e * 3 + 2];
    const int cell = mort12(cellcoord(px), cellcoord(py), cellcoord(pz));
    uint32_t* cnt = (uint32_t*)(ws + WS_CNT);
    const uint16_t* off16 = (const uint16_t*)(ws + WS_OFF);
    const uint32_t r = atomicAdd(&cnt[cell], 1u);
    const int pos = (int)off16[cell] + (int)r;
    f32x4* p4 = (f32x4*)(ws + WS_P4);
    f32x4 o; o.x = px; o.y = py; o.z = pz; o.w = __int_as_float(e);
    p4[pos] = o;
}

// ---------------------------------------------------------------------------
// Query morton-sort kernels (counting sort over 4096 cells, same pattern)
// ---------------------------------------------------------------------------
__global__ __launch_bounds__(256)
void q_init(float* __restrict__ ws) {
    const int t = blockIdx.x * 256 + threadIdx.x;
    uint32_t* qcnt = (uint32_t*)(ws + WS_QCNT);
    if (t < 4096) qcnt[t] = 0u;
}

__global__ __launch_bounds__(256)
void q_count(const float* __restrict__ pos_h, float* __restrict__ ws) {
    const int e = blockIdx.x * 256 + threadIdx.x;
    if (e >= NH) return;
    const int cell = mort12(cellcoord(pos_h[e * 3 + 0]),
                            cellcoord(pos_h[e * 3 + 1]),
                            cellcoord(pos_h[e * 3 + 2]));
    atomicAdd(&((uint32_t*)(ws + WS_QCNT))[cell], 1u);
}

__global__ __launch_bounds__(1024)
void q_scan(float* __restrict__ ws) {
    __shared__ uint32_t s_c[1024];
    const int tid = threadIdx.x;
    uint32_t* qcnt = (uint32_t*)(ws + WS_QCNT);
    uint16_t* qoff = (uint16_t*)(ws + WS_QOFF);
    const int base = tid * 4;
    const uint32_t v0 = qcnt[base + 0], v1 = qcnt[base + 1];
    const uint32_t v2 = qcnt[base + 2], v3 = qcnt[base + 3];
    const uint32_t s = v0 + v1 + v2 + v3;
    s_c[tid] = s;
    __syncthreads();
    for (int o = 1; o < 1024; o <<= 1) {
        const uint32_t t = (tid >= o) ? s_c[tid - o] : 0u;
        __syncthreads();
        s_c[tid] += t;
        __syncthreads();
    }
    uint32_t p = s_c[tid] - s;
    qoff[base + 0] = (uint16_t)p;           p += v0;
    qoff[base + 1] = (uint16_t)p;           p += v1;
    qoff[base + 2] = (uint16_t)p;           p += v2;
    qoff[base + 3] = (uint16_t)p;
    if (tid == 1023) qoff[4096] = (uint16_t)NH;
    qcnt[base + 0] = 0u; qcnt[base + 1] = 0u; qcnt[base + 2] = 0u; qcnt[base + 3] = 0u;
}

__global__ __launch_bounds__(256)
void q_scatter(const float* __restrict__ pos_h, float* __restrict__ ws) {
    const int e = blockIdx.x * 256 + threadIdx.x;
    if (e >= NH) return;
    const int cell = mort12(cellcoord(pos_h[e * 3 + 0]),
                            cellcoord(pos_h[e * 3 + 1]),
                            cellcoord(pos_h[e * 3 + 2]));
    uint32_t* qcnt = (uint32_t*)(ws + WS_QCNT);
    const uint16_t* qoff = (const uint16_t*)(ws + WS_QOFF);
    const uint32_t r = atomicAdd(&qcnt[cell], 1u);
    ((uint16_t*)(ws + WS_QPERM))[(int)qoff[cell] + (int)r] = (uint16_t)e;
}

// ---------------------------------------------------------------------------
// Query kernel v5: one wave per SORTED query (morton-order -> L1 locality +
// uniform block cost). Selection logic identical to verified R8; cell
// metadata batched via shfl to cut dependent LDS reads.
// ---------------------------------------------------------------------------
#define QBLK  8
#define PLCAP 128
#define CCAP  192
#define MCAP  128
#define INFKEY 0xFFFFFFFFFFFFFFFFull

__global__ __launch_bounds__(512, 8)
void query_kernel(const float* __restrict__ x,
                  const float* __restrict__ pos_h,
                  const float* __restrict__ ws,
                  float* __restrict__ out)
{
    __shared__ float    s_blo[512][4];          // 8 KB parent content lo
    __shared__ float    s_bhi[512][4];          // 8 KB parent content hi
    __shared__ uint16_t s_off[4100];            // 8.2 KB cell CSR offsets
    __shared__ uint16_t s_pl[QBLK][PLCAP];      // 2 KB passing parents
    __shared__ uint16_t s_cell[QBLK][CCAP];     // 3 KB passing cells
    __shared__ uint16_t s_cand[QBLK][MCAP];     // 2 KB candidate slots
    __shared__ float    s_wd2[QBLK][KSEL];      // winner d2 -> norm weight
    __shared__ uint16_t s_widx[QBLK][KSEL];     // winner slot -> orig idx
    // ~33 KB -> 4 blocks/CU (32 waves) at launch_bounds(512,8)

    const int tid  = threadIdx.x;
    const int lane = tid & 63;
    const int wid  = tid >> 6;
    const int gq   = blockIdx.x * QBLK + wid;           // sorted index
    const int sq   = (int)((const uint16_t*)(ws + WS_QPERM))[gq]; // original id

    for (int i = tid; i < 2048; i += 512) {
        ((float*)s_blo)[i] = ws[WS_PBLO + i];
        ((float*)s_bhi)[i] = ws[WS_PBHI + i];
    }
    {
        const uint16_t* og = (const uint16_t*)(ws + WS_OFF);
        for (int i = tid; i < 4097; i += 512) s_off[i] = og[i];
    }
    __syncthreads();

    const f32x4* p4 = (const f32x4*)(ws + WS_P4);
    const float qx = pos_h[(size_t)sq * 3 + 0];
    const float qy = pos_h[(size_t)sq * 3 + 1];
    const float qz = pos_h[(size_t)sq * 3 + 2];
    const unsigned long long lt = (1ull << lane) - 1ull;

    // ---- tau0 = 32nd smallest over 64 REAL points (morton window) ----
    const int qcell = mort12(cellcoord(qx), cellcoord(qy), cellcoord(qz));
    const int w0 = imin(imax((int)s_off[qcell] - 24, 0), NL - 64);
    float v = dist2f(p4[w0 + lane], qx, qy, qz);
#pragma unroll
    for (int k2 = 2; k2 <= 64; k2 <<= 1) {
#pragma unroll
        for (int jj = k2 >> 1; jj >= 1; jj >>= 1) {
            const float o     = __shfl_xor(v, jj);
            const bool  up    = ((lane & k2) == 0);
            const bool  lower = ((lane & jj) == 0);
            v = (lower == up) ? fminf(v, o) : fmaxf(v, o);
        }
    }
    const float tau0r = __shfl(v, 31);
    const float tau0m = tau0r * 1.00002f + 1e-6f;

    // ---- parent filter (exact content bounds), 8 parents/lane ----
    int npar = 0;
#pragma unroll
    for (int r = 0; r < 8; ++r) {
        const int c = r * 64 + lane;
        const float ddx = fmaxf(fmaxf(s_blo[c][0] - qx, qx - s_bhi[c][0]), 0.0f);
        const float ddy = fmaxf(fmaxf(s_blo[c][1] - qy, qy - s_bhi[c][1]), 0.0f);
        const float ddz = fmaxf(fmaxf(s_blo[c][2] - qz, qz - s_bhi[c][2]), 0.0f);
        const float dmin = fmaf(ddx, ddx, fmaf(ddy, ddy, ddz * ddz));
        const bool pass = (dmin <= tau0m);
        const unsigned long long m = __ballot(pass);
        if (pass) {
            const int pos = npar + (int)__popcll(m & lt);
            if (pos < PLCAP) s_pl[wid][pos] = (uint16_t)c;
        }
        npar += (int)__popcll(m);
    }

    bool slow = (npar > PLCAP);

    // ---- cell filter at tau0m: 8 parents/round, geometric child boxes ----
    int ncell = 0;
    if (!slow) {
        for (int pi = 0; pi < npar; pi += 8) {
            const int g   = pi + (lane >> 3);
            const int par = (g < npar) ? (int)s_pl[wid][g] : -1;
            const int cell = (par >= 0) ? (par * 8 + (lane & 7)) : 0;
            int n = 0;
            float dmc = 1e30f;
            if (par >= 0) {
                n = (int)s_off[cell + 1] - (int)s_off[cell];
                dmc = cell_dmin2(cell, qx, qy, qz);
            }
            const bool pass = (n > 0) && (dmc <= tau0m);
            const unsigned long long m = __ballot(pass);
            if (pass) {
                const int pos = ncell + (int)__popcll(m & lt);
                if (pos < CCAP) s_cell[wid][pos] = (uint16_t)cell;
            }
            ncell += (int)__popcll(m);
        }
        slow = (ncell > CCAP);
    }

    // ---- TAU-TIGHTEN: lane-min sweep, metadata batched via shfl ----
    float taum = 0.0f;
    if (!slow) {
        float rmin = INFINITY;
        for (int cb = 0; cb < ncell; cb += 64) {
            const int nb = imin(64, ncell - cb);
            int myA = 0, myN = 0;
            if (lane < nb) {
                const int c = (int)s_cell[wid][cb + lane];
                myA = (int)s_off[c];
                myN = (int)s_off[c + 1] - myA;
            }
            for (int ci = 0; ci < nb; ++ci) {
                const int a = __shfl(myA, ci);
                const int n = __shfl(myN, ci);
                for (int j = lane; j < n; j += 64)
                    rmin = fminf(rmin, dist2f(p4[a + j], qx, qy, qz));
            }
        }
        float vv = rmin;
#pragma unroll
        for (int k2 = 2; k2 <= 64; k2 <<= 1) {
#pragma unroll
            for (int jj = k2 >> 1; jj >= 1; jj >>= 1) {
                const float o     = __shfl_xor(vv, jj);
                const bool  up    = ((lane & k2) == 0);
                const bool  lower = ((lane & jj) == 0);
                vv = (lower == up) ? fminf(vv, o) : fmaxf(vv, o);
            }
        }
        const float tau1r = __shfl(vv, 31);
        taum = fminf(tau1r, tau0r) * 1.00002f + 1e-6f;   // valid bound <= tau0m

        // ---- refilter cells at taum (read-then-compact, in place) ----
        uint16_t rc0 = 0, rc1 = 0, rc2 = 0;
        bool rp0 = false, rp1 = false, rp2 = false;
        {
            const int i0 = lane, i1 = 64 + lane, i2 = 128 + lane;
            if (i0 < ncell) { rc0 = s_cell[wid][i0]; rp0 = (cell_dmin2(rc0, qx, qy, qz) <= taum); }
            if (i1 < ncell) { rc1 = s_cell[wid][i1]; rp1 = (cell_dmin2(rc1, qx, qy, qz) <= taum); }
            if (i2 < ncell) { rc2 = s_cell[wid][i2]; rp2 = (cell_dmin2(rc2, qx, qy, qz) <= taum); }
        }
        int nc2 = 0;
        {
            const unsigned long long m0 = __ballot(rp0);
            if (rp0) s_cell[wid][nc2 + (int)__popcll(m0 & lt)] = rc0;
            nc2 += (int)__popcll(m0);
            const unsigned long long m1 = __ballot(rp1);
            if (rp1) s_cell[wid][nc2 + (int)__popcll(m1 & lt)] = rc1;
            nc2 += (int)__popcll(m1);
            const unsigned long long m2 = __ballot(rp2);
            if (rp2) s_cell[wid][nc2 + (int)__popcll(m2 & lt)] = rc2;
            nc2 += (int)__popcll(m2);
        }
        ncell = nc2;
    }

    // ---- collect at taum (exact count; metadata batched via shfl) ----
    int M = 0;
    if (!slow) {
        for (int cb = 0; cb < ncell; cb += 64) {
            const int nb = imin(64, ncell - cb);
            int myA = 0, myN = 0;
            if (lane < nb) {
                const int c = (int)s_cell[wid][cb + lane];
                myA = (int)s_off[c];
                myN = (int)s_off[c + 1] - myA;
            }
            for (int ci = 0; ci < nb; ++ci) {
                const int a = __shfl(myA, ci);
                const int n = __shfl(myN, ci);
                for (int rr = 0; rr < n; rr += 64) {
                    const int j = rr + lane;
                    const bool hit = (j < n) &&
                        (dist2f(p4[a + j], qx, qy, qz) <= taum);
                    const unsigned long long m = __ballot(hit);
                    if (hit) {
                        const int pp = M + (int)__popcll(m & lt);
                        if (pp < MCAP) s_cand[wid][pp] = (uint16_t)(a + j);
                    }
                    M += (int)__popcll(m);
                }
            }
        }
        slow = (M > MCAP);
        // M >= 32 guaranteed: the >=32 points with d<=tau1 lie in kept cells
    }

    // =================== FAST PATH: fp64 re-rank of <=128 ===================
    if (!slow) {
        const double axd = (double)qx, ayd = (double)qy, azd = (double)qz;
        const int i0 = (2 * lane     < M) ? (int)s_cand[wid][2 * lane]     : -1;
        const int i1 = (2 * lane + 1 < M) ? (int)s_cand[wid][2 * lane + 1] : -1;
        float f0 = INFINITY, f1 = INFINITY;
        if (i0 >= 0) {
            const f32x4 p = p4[i0];
            const double dx = (double)p.x - axd, dy = (double)p.y - ayd, dz = (double)p.z - azd;
            f0 = (float)(dx * dx + dy * dy + dz * dz);
        }
        if (i1 >= 0) {
            const f32x4 p = p4[i1];
            const double dx = (double)p.x - axd, dy = (double)p.y - ayd, dz = (double)p.z - azd;
            f1 = (float)(dx * dx + dy * dy + dz * dz);
        }
        int v0 = __float_as_int(f0);
        int v1 = __float_as_int(f1);
#pragma unroll
        for (int k2 = 2; k2 <= 128; k2 <<= 1) {
            const bool up = ((lane & (k2 >> 1)) == 0);
#pragma unroll
            for (int j = k2 >> 1; j >= 2; j >>= 1) {
                const int  xo    = j >> 1;
                const bool lower = ((lane & xo) == 0);
                const int o0 = __shfl_xor(v0, xo);
                const int o1 = __shfl_xor(v1, xo);
                v0 = (lower == up) ? imin(v0, o0) : imax(v0, o0);
                v1 = (lower == up) ? imin(v1, o1) : imax(v1, o1);
            }
            const int mn = imin(v0, v1), mx = imax(v0, v1);
            v0 = up ? mn : mx;
            v1 = up ? mx : mn;
        }
        const int tau32 = __shfl(v1, 15);   // rank-31 key (32nd smallest)

        const bool a0 = (i0 >= 0) && (__float_as_int(f0) <= tau32);
        const bool a1 = (i1 >= 0) && (__float_as_int(f1) <= tau32);
        const unsigned long long b0 = __ballot(a0);
        const unsigned long long b1 = __ballot(a1);
        const int cb2 = (int)__popcll(b0 & lt) + (int)__popcll(b1 & lt);
        const int p0 = cb2;
        const int p1 = cb2 + (a0 ? 1 : 0);
        if (a0 && p0 < KSEL) { s_wd2[wid][p0] = f0; s_widx[wid][p0] = (uint16_t)i0; }
        if (a1 && p1 < KSEL) { s_wd2[wid][p1] = f1; s_widx[wid][p1] = (uint16_t)i1; }
    }

    // ============ SLOW PATH (rare): list-free streaming top-64 ============
    if (slow) {
        u64 L = INFKEY;
#pragma unroll 1
        for (int r = 0; r < 8; ++r) {
            const int c = r * 64 + lane;
            const float ddx = fmaxf(fmaxf(s_blo[c][0] - qx, qx - s_bhi[c][0]), 0.0f);
            const float ddy = fmaxf(fmaxf(s_blo[c][1] - qy, qy - s_bhi[c][1]), 0.0f);
            const float ddz = fmaxf(fmaxf(s_blo[c][2] - qz, qz - s_bhi[c][2]), 0.0f);
            const float dmin = fmaf(ddx, ddx, fmaf(ddy, ddy, ddz * ddz));
            unsigned long long pm = __ballot(dmin <= tau0m);
            while (pm) {
                const int pl = __ffsll(pm) - 1; pm &= pm - 1;
                const int par = r * 64 + pl;
                const int a = (int)s_off[par * 8];
                const int e = (int)s_off[par * 8 + 8];   // children contiguous
                for (int rr = a; rr < e; rr += 64) {
                    const int j = rr + lane;
                    u64 b = INFKEY;
                    if (j < e) {
                        const float d2 = dist2f(p4[j], qx, qy, qz);
                        b = (((u64)__float_as_uint(d2)) << 16) | (u64)j;
                    }
                    const u64 worst = __shfl(L, 63);
                    if (!__any(b < worst)) continue;
#pragma unroll
                    for (int k2 = 2; k2 <= 64; k2 <<= 1) {
#pragma unroll
                        for (int jj = k2 >> 1; jj >= 1; jj >>= 1) {
                            const u64  o     = __shfl_xor(b, jj);
                            const bool up    = ((lane & k2) == 0);
                            const bool lower = ((lane & jj) == 0);
                            b = (lower == up) ? umin64(b, o) : umax64(b, o);
                        }
                    }
                    L = umin64(L, __shfl_xor(b, 63));
#pragma unroll
                    for (int jj = 32; jj >= 1; jj >>= 1) {
                        const u64 o = __shfl_xor(L, jj);
                        L = ((lane & jj) == 0) ? umin64(L, o) : umax64(L, o);
                    }
                }
            }
        }
        const double axd = (double)qx, ayd = (double)qy, azd = (double)qz;
        const bool valid = (L != INFKEY);
        const int  slot  = (int)(L & 0xFFFFull);
        float fd2 = INFINITY;
        if (valid) {
            const f32x4 p = p4[slot];
            const double dx = (double)p.x - axd;
            const double dy = (double)p.y - ayd;
            const double dz = (double)p.z - azd;
            fd2 = (float)(dx * dx + dy * dy + dz * dz);
        }
        u64 k2v = (((u64)__float_as_uint(fd2)) << 16)
                | (u64)(valid ? slot : 0xFFFF);
#pragma unroll
        for (int k2 = 2; k2 <= 64; k2 <<= 1) {
#pragma unroll
            for (int jj = k2 >> 1; jj >= 1; jj >>= 1) {
                const u64  o     = __shfl_xor(k2v, jj);
                const bool up    = ((lane & k2) == 0);
                const bool lower = ((lane & jj) == 0);
                k2v = (lower == up) ? umin64(k2v, o) : umax64(k2v, o);
            }
        }
        if (lane < KSEL) {
            s_wd2[wid][lane]  = __uint_as_float((uint32_t)(k2v >> 16));
            s_widx[wid][lane] = (uint16_t)(k2v & 0xFFFFull);
        }
    }

    // ---- common: weights (slot -> orig, normalize once) ----
    {
        float w = 0.0f;
        int orig = 0;
        if (lane < KSEL) {
            const int slot = (int)s_widx[wid][lane];
            orig = __float_as_int(p4[slot].w);
            w = __builtin_amdgcn_rcpf(fmaxf(s_wd2[wid][lane], 1e-16f));
        }
        float wsum = w;
#pragma unroll
        for (int d = 1; d < 32; d <<= 1) wsum += __shfl_xor(wsum, d);
        if (lane < KSEL) {
            s_wd2[wid][lane]  = w * __builtin_amdgcn_rcpf(wsum);
            s_widx[wid][lane] = (uint16_t)orig;
        }
    }

    // ---- feature gather + weighted average (writes to ORIGINAL slot) ----
    f32x2 acc = (f32x2){0.0f, 0.0f};
#pragma unroll 8
    for (int kk = 0; kk < KSEL; ++kk) {
        const float w    = s_wd2[wid][kk];
        const int   orig = (int)s_widx[wid][kk];
        const f32x2 r2 = *(const f32x2*)(x + (size_t)orig * FDIM + 2 * lane);
        acc.x = fmaf(w, r2.x, acc.x);
        acc.y = fmaf(w, r2.y, acc.y);
    }
    *(f32x2*)(out + (size_t)sq * FDIM + 2 * lane) = acc;
}

// ---------------------------------------------------------------------------
// Fallback: verified round-2 brute-force kernel (used if ws too small)
// ---------------------------------------------------------------------------
#define CHUNK  1024
#define NCHUNK (NL / CHUNK)
#define QPW    4
#define NWAVES 8
#define BLOCK  (NWAVES * 64)
#define QPB    (NWAVES * QPW)
#define BUFCAP 128

__device__ __forceinline__ f32x2 pk_fma_lo(f32x2 s0, f32x2 s1, f32x2 s2) {
    f32x2 d;
    asm("v_pk_fma_f32 %0, %1, %2, %3 op_sel:[0,0,0] op_sel_hi:[1,0,1]"
        : "=v"(d) : "v"(s0), "v"(s1), "v"(s2));
    return d;
}
__device__ __forceinline__ f32x2 pk_fma_hi(f32x2 s0, f32x2 s1, f32x2 s2) {
    f32x2 d;
    asm("v_pk_fma_f32 %0, %1, %2, %3 op_sel:[0,1,0] op_sel_hi:[1,1,1]"
        : "=v"(d) : "v"(s0), "v"(s1), "v"(s2));
    return d;
}

__global__ __launch_bounds__(BLOCK, 8)
void knn_interp_kernel(const float* __restrict__ x,
                       const float* __restrict__ pos_l,
                       const float* __restrict__ pos_h,
                       float* __restrict__ out)
{
    __shared__ f32x2    s_x[CHUNK/2], s_y[CHUNK/2], s_z[CHUNK/2], s_w[CHUNK/2];
    __shared__ uint16_t s_idx[QPB][BUFCAP];
    __shared__ uint32_t s_cnt[QPB];
    __shared__ float    s_wd2[QPB][KSEL];
    __shared__ uint16_t s_widx[QPB][KSEL];

    const int tid   = threadIdx.x;
    const int lane  = tid & 63;
    const int wid   = tid >> 6;
    const int qbase = blockIdx.x * QPB + wid * QPW;

    f32x2 hxq[QPW/2], hyq[QPW/2], hzq[QPW/2];
#pragma unroll
    for (int j = 0; j < QPW/2; ++j) {
        const float a0x = pos_h[(size_t)(qbase + 2*j    ) * 3 + 0];
        const float a0y = pos_h[(size_t)(qbase + 2*j    ) * 3 + 1];
        const float a0z = pos_h[(size_t)(qbase + 2*j    ) * 3 + 2];
        const float a1x = pos_h[(size_t)(qbase + 2*j + 1) * 3 + 0];
        const float a1y = pos_h[(size_t)(qbase + 2*j + 1) * 3 + 1];
        const float a1z = pos_h[(size_t)(qbase + 2*j + 1) * 3 + 2];
        hxq[j] = (f32x2){-2.0f * a0x, -2.0f * a1x};
        hyq[j] = (f32x2){-2.0f * a0y, -2.0f * a1y};
        hzq[j] = (f32x2){-2.0f * a0z, -2.0f * a1z};
    }
    f32x2 rminp[QPW];
#pragma unroll
    for (int q = 0; q < QPW; ++q) rminp[q] = (f32x2){INFINITY, INFINITY};

    for (int c = 0; c < NCHUNK; ++c) {
        __syncthreads();
        for (int i = tid; i < CHUNK/2; i += BLOCK) {
            const float* p = pos_l + (size_t)(c * CHUNK + 2 * i) * 3;
            const f32x2 A = *(const f32x2*)(p + 0);
            const f32x2 B = *(const f32x2*)(p + 2);
            const f32x2 C = *(const f32x2*)(p + 4);
            s_x[i] = (f32x2){A.x, B.y};
            s_y[i] = (f32x2){A.y, C.x};
            s_z[i] = (f32x2){B.x, C.y};
            s_w[i] = (f32x2){fmaf(A.x, A.x, fmaf(A.y, A.y, B.x * B.x)),
                             fmaf(B.y, B.y, fmaf(C.x, C.x, C.y * C.y))};
        }
        __syncthreads();
#pragma unroll
        for (int i = 0; i < CHUNK/128; ++i) {
            const int pi = i * 64 + lane;
            const f32x2 xp = s_x[pi], yp = s_y[pi], zp = s_z[pi], wp = s_w[pi];
#pragma unroll
            for (int j = 0; j < QPW/2; ++j) {
                f32x2 t0 = pk_fma_lo(xp, hxq[j], wp);
                t0 = pk_fma_lo(yp, hyq[j], t0);
                t0 = pk_fma_lo(zp, hzq[j], t0);
                rminp[2*j].x = fminf(rminp[2*j].x, t0.x);
                rminp[2*j].y = fminf(rminp[2*j].y, t0.y);
                f32x2 t1 = pk_fma_hi(xp, hxq[j], wp);
                t1 = pk_fma_hi(yp, hyq[j], t1);
                t1 = pk_fma_hi(zp, hzq[j], t1);
                rminp[2*j+1].x = fminf(rminp[2*j+1].x, t1.x);
                rminp[2*j+1].y = fminf(rminp[2*j+1].y, t1.y);
            }
        }
    }
    float tau_acc[QPW];
#pragma unroll
    for (int q = 0; q < QPW; ++q) {
        float v = fminf(rminp[q].x, rminp[q].y);
#pragma unroll
        for (int k = 2; k <= 64; k <<= 1) {
#pragma unroll
            for (int jj = k >> 1; jj >= 1; jj >>= 1) {
                const float o     = __shfl_xor(v, jj);
                const bool  up    = ((lane & k) == 0);
                const bool  lower = ((lane & jj) == 0);
                v = (lower == up) ? fminf(v, o) : fmaxf(v, o);
            }
        }
        tau_acc[q] = __shfl(v, 31) + 1e-4f;
    }
    if (tid < QPB) s_cnt[tid] = 0;
    for (int c = 0; c < NCHUNK; ++c) {
        __syncthreads();
        for (int i = tid; i < CHUNK/2; i += BLOCK) {
            const float* p = pos_l + (size_t)(c * CHUNK + 2 * i) * 3;
            const f32x2 A = *(const f32x2*)(p + 0);
            const f32x2 B = *(const f32x2*)(p + 2);
            const f32x2 C = *(const f32x2*)(p + 4);
            s_x[i] = (f32x2){A.x, B.y};
            s_y[i] = (f32x2){A.y, C.x};
            s_z[i] = (f32x2){B.x, C.y};
            s_w[i] = (f32x2){fmaf(A.x, A.x, fmaf(A.y, A.y, B.x * B.x)),
                             fmaf(B.y, B.y, fmaf(C.x, C.x, C.y * C.y))};
        }
        __syncthreads();
#pragma unroll 2
        for (int i = 0; i < CHUNK/128; ++i) {
            const int pi = i * 64 + lane;
            const f32x2 xp = s_x[pi], yp = s_y[pi], zp = s_z[pi], wp = s_w[pi];
            const int g0 = c * CHUNK + 2 * pi;
#pragma unroll
            for (int j = 0; j < QPW/2; ++j) {
                f32x2 t0 = pk_fma_lo(xp, hxq[j], wp);
                t0 = pk_fma_lo(yp, hyq[j], t0);
                t0 = pk_fma_lo(zp, hzq[j], t0);
                f32x2 t1 = pk_fma_hi(xp, hxq[j], wp);
                t1 = pk_fma_hi(yp, hyq[j], t1);
                t1 = pk_fma_hi(zp, hzq[j], t1);
                const int q0 = wid * QPW + 2*j;
                if (__any(fminf(t0.x, t0.y) <= tau_acc[2*j])) {
                    if (t0.x <= tau_acc[2*j]) {
                        const uint32_t p0 = atomicAdd(&s_cnt[q0], 1u);
                        if (p0 < BUFCAP) s_idx[q0][p0] = (uint16_t)g0;
                    }
                    if (t0.y <= tau_acc[2*j]) {
                        const uint32_t p0 = atomicAdd(&s_cnt[q0], 1u);
                        if (p0 < BUFCAP) s_idx[q0][p0] = (uint16_t)(g0 + 1);
                    }
                }
                if (__any(fminf(t1.x, t1.y) <= tau_acc[2*j+1])) {
                    if (t1.x <= tau_acc[2*j+1]) {
                        const uint32_t p0 = atomicAdd(&s_cnt[q0 + 1], 1u);
                        if (p0 < BUFCAP) s_idx[q0 + 1][p0] = (uint16_t)g0;
                    }
                    if (t1.y <= tau_acc[2*j+1]) {
                        const uint32_t p0 = atomicAdd(&s_cnt[q0 + 1], 1u);
                        if (p0 < BUFCAP) s_idx[q0 + 1][p0] = (uint16_t)(g0 + 1);
                    }
                }
            }
        }
    }
#pragma unroll 1
    for (int q = 0; q < QPW; ++q) {
        const int qq = wid * QPW + q;
        uint32_t M = s_cnt[qq];
        if (M > BUFCAP) M = BUFCAP;
        const double axd = (double)pos_h[(size_t)(qbase + q) * 3 + 0];
        const double ayd = (double)pos_h[(size_t)(qbase + q) * 3 + 1];
        const double azd = (double)pos_h[(size_t)(qbase + q) * 3 + 2];
        const int i0 = ((uint32_t)(2 * lane)     < M) ? (int)s_idx[qq][2 * lane]     : -1;
        const int i1 = ((uint32_t)(2 * lane + 1) < M) ? (int)s_idx[qq][2 * lane + 1] : -1;
        float f0 = INFINITY, f1 = INFINITY;
        if (i0 >= 0) {
            const double dx = (double)pos_l[i0 * 3 + 0] - axd;
            const double dy = (double)pos_l[i0 * 3 + 1] - ayd;
            const double dz = (double)pos_l[i0 * 3 + 2] - azd;
            f0 = (float)(dx * dx + dy * dy + dz * dz);
        }
        if (i1 >= 0) {
            const double dx = (double)pos_l[i1 * 3 + 0] - axd;
            const double dy = (double)pos_l[i1 * 3 + 1] - ayd;
            const double dz = (double)pos_l[i1 * 3 + 2] - azd;
            f1 = (float)(dx * dx + dy * dy + dz * dz);
        }
        int v0 = __float_as_int(f0);
        int v1 = __float_as_int(f1);
#pragma unroll
        for (int k = 2; k <= 128; k <<= 1) {
            const bool up = ((lane & (k >> 1)) == 0);
#pragma unroll
            for (int j = k >> 1; j >= 2; j >>= 1) {
                const int  xo    = j >> 1;
                const bool lower = ((lane & xo) == 0);
                const int o0 = __shfl_xor(v0, xo);
                const int o1 = __shfl_xor(v1, xo);
                v0 = (lower == up) ? imin(v0, o0) : imax(v0, o0);
                v1 = (lower == up) ? imin(v1, o1) : imax(v1, o1);
            }
            const int mn = imin(v0, v1), mx = imax(v0, v1);
            v0 = up ? mn : mx;
            v1 = up ? mx : mn;
        }
        const int tau32 = __shfl(v1, 15);
        const bool a0 = (i0 >= 0) && (__float_as_int(f0) <= tau32);
        const bool a1 = (i1 >= 0) && (__float_as_int(f1) <= tau32);
        const unsigned long long b0 = __ballot(a0);
        const unsigned long long b1 = __ballot(a1);
        const unsigned long long mb = (lane == 63) ? 0x7FFFFFFFFFFFFFFFull
                                                   : ((1ull << (lane + 1)) - 1ull) >> 1;
        const int base = __popcll(b0 & mb) + __popcll(b1 & mb);
        const int p0 = base;
        const int p1 = base + (a0 ? 1 : 0);
        if (a0 && p0 < KSEL) { s_wd2[qq][p0] = f0; s_widx[qq][p0] = (uint16_t)i0; }
        if (a1 && p1 < KSEL) { s_wd2[qq][p1] = f1; s_widx[qq][p1] = (uint16_t)i1; }
    }
#pragma unroll 1
    for (int q = 0; q < QPW; ++q) {
        const int qq = wid * QPW + q;
        const int gq = qbase + q;
        f32x2 acc = (f32x2){0.0f, 0.0f};
        float wsum = 0.0f;
#pragma unroll 8
        for (int kk = 0; kk < KSEL; ++kk) {
            const float d2 = s_wd2[qq][kk];
            const float w  = __builtin_amdgcn_rcpf(fmaxf(d2, 1e-16f));
            const int  idx = (int)s_widx[qq][kk];
            const f32x2 r2 = *(const f32x2*)(x + (size_t)idx * FDIM + 2 * lane);
            acc.x = fmaf(w, r2.x, acc.x);
            acc.y = fmaf(w, r2.y, acc.y);
            wsum += w;
        }
        const float invw = __builtin_amdgcn_rcpf(wsum);
        out[(size_t)gq * FDIM + 2 * lane]     = acc.x * invw;
        out[(size_t)gq * FDIM + 2 * lane + 1] = acc.y * invw;
    }
}

// ---------------------------------------------------------------------------
extern "C" void kernel_launch(void* const* d_in, const int* in_sizes, int n_in,
                              void* d_out, int out_size, void* d_ws, size_t ws_size,
                              hipStream_t stream) {
    const float* x     = (const float*)d_in[0];
    const float* pos_l = (const float*)d_in[1];
    const float* pos_h = (const float*)d_in[2];
    float* out = (float*)d_out;

    if (d_ws != nullptr && ws_size >= (size_t)WS_BYTES) {
        float* ws = (float*)d_ws;
        hipLaunchKernelGGL(k_init,    dim3(16),  dim3(256),  0, stream, ws);
        hipLaunchKernelGGL(k_count,   dim3(32),  dim3(256),  0, stream, pos_l, ws);
        hipLaunchKernelGGL(k_scan,    dim3(1),   dim3(1024), 0, stream, ws);
        hipLaunchKernelGGL(k_scatter, dim3(32),  dim3(256),  0, stream, pos_l, ws);
        hipLaunchKernelGGL(q_init,    dim3(16),  dim3(256),  0, stream, ws);
        hipLaunchKernelGGL(q_count,   dim3(128), dim3(256),  0, stream, pos_h, ws);
        hipLaunchKernelGGL(q_scan,    dim3(1),   dim3(1024), 0, stream, ws);
        hipLaunchKernelGGL(q_scatter, dim3(128), dim3(256),  0, stream, pos_h, ws);
        hipLaunchKernelGGL(query_kernel, dim3(NH / QBLK), dim3(512), 0, stream,
                           x, pos_h, ws, out);
    } else {
        hipLaunchKernelGGL(knn_interp_kernel, dim3(NH / QPB), dim3(BLOCK), 0, stream,
                           x, pos_l, pos_h, out);
    }
}

// Round 10
// 265.981 us; speedup vs baseline: 2.2269x; 1.8954x over previous
//
#include <hip/hip_runtime.h>
#include <stdint.h>

#define NL    8192
#define NH    32768
#define FDIM  128
#define KSEL  32

// 16x16x16 morton grid over [-4,4)^3 (clamped), cell size 0.5
#define GLO   (-4.0f)
#define GINV  (2.0f)

typedef float f32x2 __attribute__((ext_vector_type(2)));
typedef float f32x4 __attribute__((ext_vector_type(4)));
typedef unsigned long long u64;

__device__ __forceinline__ int imin(int a, int b) { return a < b ? a : b; }
__device__ __forceinline__ int imax(int a, int b) { return a > b ? a : b; }
__device__ __forceinline__ u64 umin64(u64 a, u64 b) { return a < b ? a : b; }
__device__ __forceinline__ u64 umax64(u64 a, u64 b) { return a > b ? a : b; }

// ---------------------------------------------------------------------------
// Workspace layout (float offsets). Total 65804 floats = 263216 bytes.
// (identical to the VERIFIED round-9 layout)
// ---------------------------------------------------------------------------
#define WS_P4    0       // 8192 * float4 (x,y,z, w=orig index bits)
#define WS_PBLO  32768   // 512 parents * 4 (u32-encoded, decoded to float)
#define WS_PBHI  34816   // 512 parents * 4
#define WS_OFF   36864   // u16[4097] CSR cell offsets
#define WS_POFF  38916   // u16[513]  parent offsets
#define WS_CNT   39176   // u32[4096] counts -> cursors
#define WS_QOFF  43272   // u16[4097] query CSR offsets
#define WS_QPERM 45324   // u16[32768] sorted->orig query ids
#define WS_QCNT  61708   // u32[4096] query counts -> cursors
#define WS_FLOATS 65804
#define WS_BYTES  (WS_FLOATS * 4)

__device__ __forceinline__ uint32_t ordf(float f) {
    uint32_t u = __float_as_uint(f);
    return (u & 0x80000000u) ? ~u : (u | 0x80000000u);
}
__device__ __forceinline__ float iordf(uint32_t e) {
    return (e & 0x80000000u) ? __uint_as_float(e & 0x7FFFFFFFu)
                             : __uint_as_float(~e);
}
__device__ __forceinline__ int cellcoord(float p) {
    return imin(imax((int)floorf((p - GLO) * GINV), 0), 15);
}
__device__ __forceinline__ int mort12(int ix, int iy, int iz) {
    int m = 0;
#pragma unroll
    for (int b = 0; b < 4; ++b)
        m |= (((ix >> b) & 1) << (3 * b + 2)) |
             (((iy >> b) & 1) << (3 * b + 1)) |
             (((iz >> b) & 1) << (3 * b));
    return m;
}
__device__ __forceinline__ int deint4(int id, int sh) {   // bits at 3k+sh
    int v = 0;
#pragma unroll
    for (int b = 0; b < 4; ++b) v |= ((id >> (3 * b + sh)) & 1) << b;
    return v;
}
__device__ __forceinline__ float dist2f(f32x4 p, float qx, float qy, float qz) {
    const float dx = qx - p.x, dy = qy - p.y, dz = qz - p.z;
    return fmaf(dx, dx, fmaf(dy, dy, dz * dz));
}
// geometric dmin^2 to cell box (edge cells extended to infinity)
__device__ __forceinline__ float cell_dmin2(int cell, float qx, float qy, float qz) {
    const int cix = deint4(cell, 2), ciy = deint4(cell, 1), ciz = deint4(cell, 0);
    const float lx = (cix == 0)  ? -1e30f : GLO + 0.5f * cix;
    const float hx = (cix == 15) ?  1e30f : GLO + 0.5f * (cix + 1);
    const float ly = (ciy == 0)  ? -1e30f : GLO + 0.5f * ciy;
    const float hy = (ciy == 15) ?  1e30f : GLO + 0.5f * (ciy + 1);
    const float lz = (ciz == 0)  ? -1e30f : GLO + 0.5f * ciz;
    const float hz = (ciz == 15) ?  1e30f : GLO + 0.5f * (ciz + 1);
    const float gx = fmaxf(fmaxf(lx - qx, qx - hx), 0.0f);
    const float gy = fmaxf(fmaxf(ly - qy, qy - hy), 0.0f);
    const float gz = fmaxf(fmaxf(lz - qz, qz - hz), 0.0f);
    return fmaf(gx, gx, fmaf(gy, gy, gz * gz));
}

// ---------------------------------------------------------------------------
// Build kernels (VERIFIED rounds 5-9, unchanged)
// ---------------------------------------------------------------------------
__global__ __launch_bounds__(256)
void k_init(float* __restrict__ ws) {
    const int t = blockIdx.x * 256 + threadIdx.x;
    uint32_t* cnt = (uint32_t*)(ws + WS_CNT);
    uint32_t* elo = (uint32_t*)(ws + WS_PBLO);
    uint32_t* ehi = (uint32_t*)(ws + WS_PBHI);
    if (t < 4096) cnt[t] = 0u;
    if (t < 2048) { elo[t] = 0xFFFFFFFFu; ehi[t] = 0u; }
}

__global__ __launch_bounds__(256)
void k_count(const float* __restrict__ pos_l, float* __restrict__ ws) {
    const int e = blockIdx.x * 256 + threadIdx.x;
    if (e >= NL) return;
    const float px = pos_l[e * 3 + 0];
    const float py = pos_l[e * 3 + 1];
    const float pz = pos_l[e * 3 + 2];
    const int cell = mort12(cellcoord(px), cellcoord(py), cellcoord(pz));
    uint32_t* cnt = (uint32_t*)(ws + WS_CNT);
    uint32_t* elo = (uint32_t*)(ws + WS_PBLO);
    uint32_t* ehi = (uint32_t*)(ws + WS_PBHI);
    atomicAdd(&cnt[cell], 1u);
    const int par = cell >> 3;
    atomicMin(&elo[par * 4 + 0], ordf(px));
    atomicMin(&elo[par * 4 + 1], ordf(py));
    atomicMin(&elo[par * 4 + 2], ordf(pz));
    atomicMax(&ehi[par * 4 + 0], ordf(px));
    atomicMax(&ehi[par * 4 + 1], ordf(py));
    atomicMax(&ehi[par * 4 + 2], ordf(pz));
}

__global__ __launch_bounds__(1024)
void k_scan(float* __restrict__ ws) {
    __shared__ uint32_t s_c[1024];
    const int tid = threadIdx.x;
    uint32_t* cnt = (uint32_t*)(ws + WS_CNT);
    uint16_t* off16  = (uint16_t*)(ws + WS_OFF);
    uint16_t* poff16 = (uint16_t*)(ws + WS_POFF);

    const int base = tid * 4;
    const uint32_t v0 = cnt[base + 0], v1 = cnt[base + 1];
    const uint32_t v2 = cnt[base + 2], v3 = cnt[base + 3];
    const uint32_t s = v0 + v1 + v2 + v3;
    s_c[tid] = s;
    __syncthreads();
    for (int o = 1; o < 1024; o <<= 1) {
        const uint32_t t = (tid >= o) ? s_c[tid - o] : 0u;
        __syncthreads();
        s_c[tid] += t;
        __syncthreads();
    }
    uint32_t p = s_c[tid] - s;
    if ((tid & 1) == 0) poff16[tid >> 1] = (uint16_t)p;
    if (tid == 0)       poff16[512]      = (uint16_t)NL;
    off16[base + 0] = (uint16_t)p;           p += v0;
    off16[base + 1] = (uint16_t)p;           p += v1;
    off16[base + 2] = (uint16_t)p;           p += v2;
    off16[base + 3] = (uint16_t)p;
    if (tid == 1023) off16[4096] = (uint16_t)NL;
    cnt[base + 0] = 0u; cnt[base + 1] = 0u; cnt[base + 2] = 0u; cnt[base + 3] = 0u;

    if (tid < 512) {
        uint32_t* elo = (uint32_t*)(ws + WS_PBLO);
        uint32_t* ehi = (uint32_t*)(ws + WS_PBHI);
        float* flo = ws + WS_PBLO;
        float* fhi = ws + WS_PBHI;
        const bool empty = (ehi[tid * 4 + 0] == 0u);
#pragma unroll
        for (int d = 0; d < 3; ++d) {
            const float lo = empty ?  1e30f : iordf(elo[tid * 4 + d]);
            const float hi = empty ? -1e30f : iordf(ehi[tid * 4 + d]);
            flo[tid * 4 + d] = lo;
            fhi[tid * 4 + d] = hi;
        }
        flo[tid * 4 + 3] = 0.0f;
        fhi[tid * 4 + 3] = 0.0f;
    }
}

__global__ __launch_bounds__(256)
void k_scatter(const float* __restrict__ pos_l, float* __restrict__ ws) {
    const int e = blockIdx.x * 256 + threadIdx.x;
    if (e >= NL) return;
    const float px = pos_l[e * 3 + 0];
    const float py = pos_l[e * 3 + 1];
    const float pz = pos_l[e * 3 + 2];
    const int cell = mort12(cellcoord(px), cellcoord(py), cellcoord(pz));
    uint32_t* cnt = (uint32_t*)(ws + WS_CNT);
    const uint16_t* off16 = (const uint16_t*)(ws + WS_OFF);
    const uint32_t r = atomicAdd(&cnt[cell], 1u);
    const int pos = (int)off16[cell] + (int)r;
    f32x4* p4 = (f32x4*)(ws + WS_P4);
    f32x4 o; o.x = px; o.y = py; o.z = pz; o.w = __int_as_float(e);
    p4[pos] = o;
}

// ---------------------------------------------------------------------------
// Query morton-sort kernels (VERIFIED round-9, unchanged)
// ---------------------------------------------------------------------------
__global__ __launch_bounds__(256)
void q_init(float* __restrict__ ws) {
    const int t = blockIdx.x * 256 + threadIdx.x;
    uint32_t* qcnt = (uint32_t*)(ws + WS_QCNT);
    if (t < 4096) qcnt[t] = 0u;
}

__global__ __launch_bounds__(256)
void q_count(const float* __restrict__ pos_h, float* __restrict__ ws) {
    const int e = blockIdx.x * 256 + threadIdx.x;
    if (e >= NH) return;
    const int cell = mort12(cellcoord(pos_h[e * 3 + 0]),
                            cellcoord(pos_h[e * 3 + 1]),
                            cellcoord(pos_h[e * 3 + 2]));
    atomicAdd(&((uint32_t*)(ws + WS_QCNT))[cell], 1u);
}

__global__ __launch_bounds__(1024)
void q_scan(float* __restrict__ ws) {
    __shared__ uint32_t s_c[1024];
    const int tid = threadIdx.x;
    uint32_t* qcnt = (uint32_t*)(ws + WS_QCNT);
    uint16_t* qoff = (uint16_t*)(ws + WS_QOFF);
    const int base = tid * 4;
    const uint32_t v0 = qcnt[base + 0], v1 = qcnt[base + 1];
    const uint32_t v2 = qcnt[base + 2], v3 = qcnt[base + 3];
    const uint32_t s = v0 + v1 + v2 + v3;
    s_c[tid] = s;
    __syncthreads();
    for (int o = 1; o < 1024; o <<= 1) {
        const uint32_t t = (tid >= o) ? s_c[tid - o] : 0u;
        __syncthreads();
        s_c[tid] += t;
        __syncthreads();
    }
    uint32_t p = s_c[tid] - s;
    qoff[base + 0] = (uint16_t)p;           p += v0;
    qoff[base + 1] = (uint16_t)p;           p += v1;
    qoff[base + 2] = (uint16_t)p;           p += v2;
    qoff[base + 3] = (uint16_t)p;
    if (tid == 1023) qoff[4096] = (uint16_t)NH;
    qcnt[base + 0] = 0u; qcnt[base + 1] = 0u; qcnt[base + 2] = 0u; qcnt[base + 3] = 0u;
}

__global__ __launch_bounds__(256)
void q_scatter(const float* __restrict__ pos_h, float* __restrict__ ws) {
    const int e = blockIdx.x * 256 + threadIdx.x;
    if (e >= NH) return;
    const int cell = mort12(cellcoord(pos_h[e * 3 + 0]),
                            cellcoord(pos_h[e * 3 + 1]),
                            cellcoord(pos_h[e * 3 + 2]));
    uint32_t* qcnt = (uint32_t*)(ws + WS_QCNT);
    const uint16_t* qoff = (const uint16_t*)(ws + WS_QOFF);
    const uint32_t r = atomicAdd(&qcnt[cell], 1u);
    ((uint16_t*)(ws + WS_QPERM))[(int)qoff[cell] + (int)r] = (uint16_t)e;
}

// ---------------------------------------------------------------------------
// Query kernel v6: one wave per SORTED query.
//   fast (capless until the tight phase):
//     tau0 (window) -> parent filter at tau0m (<=512, structural, NO escape)
//     -> lane-min TIGHTEN sweep over contiguous parent ranges -> tau1
//     -> refilter parents in place at taum -> cell filter at taum (CCAP
//        escape, now ~never) -> collect exact-M (MCAP escape) -> fp64 rerank
//   slow: (astronomical) verified list-free streaming u64 top-64
// ---------------------------------------------------------------------------
#define QBLK  8
#define PLCAP 512
#define CCAP  128
#define MCAP  128
#define INFKEY 0xFFFFFFFFFFFFFFFFull

__global__ __launch_bounds__(512, 8)
void query_kernel(const float* __restrict__ x,
                  const float* __restrict__ pos_h,
                  const float* __restrict__ ws,
                  float* __restrict__ out)
{
    __shared__ float    s_blo[512][4];          // 8 KB parent content lo
    __shared__ float    s_bhi[512][4];          // 8 KB parent content hi
    __shared__ uint16_t s_off[4100];            // 8.2 KB cell CSR offsets
    __shared__ uint16_t s_poff[516];            // 1 KB parent CSR offsets
    __shared__ uint16_t s_pl[QBLK][PLCAP];      // 8 KB passing parents (ALL fit)
    __shared__ uint16_t s_cell[QBLK][CCAP];     // 2 KB passing cells (taum)
    __shared__ uint16_t s_cand[QBLK][MCAP];     // 2 KB candidate slots
    __shared__ float    s_wd2[QBLK][KSEL];      // winner d2 -> norm weight
    __shared__ uint16_t s_widx[QBLK][KSEL];     // winner slot -> orig idx
    // ~38.7 KB -> 4 blocks/CU (32 waves) at launch_bounds(512,8)

    const int tid  = threadIdx.x;
    const int lane = tid & 63;
    const int wid  = tid >> 6;
    const int gq   = blockIdx.x * QBLK + wid;                       // sorted
    const int sq   = (int)((const uint16_t*)(ws + WS_QPERM))[gq];   // original

    for (int i = tid; i < 2048; i += 512) {
        ((float*)s_blo)[i] = ws[WS_PBLO + i];
        ((float*)s_bhi)[i] = ws[WS_PBHI + i];
    }
    {
        const uint16_t* og = (const uint16_t*)(ws + WS_OFF);
        for (int i = tid; i < 4097; i += 512) s_off[i] = og[i];
        const uint16_t* pg = (const uint16_t*)(ws + WS_POFF);
        for (int i = tid; i < 513; i += 512) s_poff[i] = pg[i];
    }
    __syncthreads();

    const f32x4* p4 = (const f32x4*)(ws + WS_P4);
    const float qx = pos_h[(size_t)sq * 3 + 0];
    const float qy = pos_h[(size_t)sq * 3 + 1];
    const float qz = pos_h[(size_t)sq * 3 + 2];
    const unsigned long long lt = (1ull << lane) - 1ull;

    // ---- tau0 = 32nd smallest over 64 REAL points (morton window) ----
    const int qcell = mort12(cellcoord(qx), cellcoord(qy), cellcoord(qz));
    const int w0 = imin(imax((int)s_off[qcell] - 24, 0), NL - 64);
    float v = dist2f(p4[w0 + lane], qx, qy, qz);
#pragma unroll
    for (int k2 = 2; k2 <= 64; k2 <<= 1) {
#pragma unroll
        for (int jj = k2 >> 1; jj >= 1; jj >>= 1) {
            const float o     = __shfl_xor(v, jj);
            const bool  up    = ((lane & k2) == 0);
            const bool  lower = ((lane & jj) == 0);
            v = (lower == up) ? fminf(v, o) : fmaxf(v, o);
        }
    }
    const float tau0r = __shfl(v, 31);
    const float tau0m = tau0r * 1.00002f + 1e-6f;

    // ---- parent filter at tau0m (exact content bounds), 8 parents/lane ----
    // NO cap escape: at most 512 parents exist and PLCAP==512.
    int npar = 0;
#pragma unroll
    for (int r = 0; r < 8; ++r) {
        const int c = r * 64 + lane;
        const float ddx = fmaxf(fmaxf(s_blo[c][0] - qx, qx - s_bhi[c][0]), 0.0f);
        const float ddy = fmaxf(fmaxf(s_blo[c][1] - qy, qy - s_bhi[c][1]), 0.0f);
        const float ddz = fmaxf(fmaxf(s_blo[c][2] - qz, qz - s_bhi[c][2]), 0.0f);
        const float dmin = fmaf(ddx, ddx, fmaf(ddy, ddy, ddz * ddz));
        const bool pass = (dmin <= tau0m);
        const unsigned long long m = __ballot(pass);
        if (pass) s_pl[wid][npar + (int)__popcll(m & lt)] = (uint16_t)c;
        npar += (int)__popcll(m);
    }

    // ---- TIGHTEN: lane-min streamed over contiguous parent ranges ----
    // tau1 = 32nd-of-64 lane minima over >=all points within tau0m-parents;
    // each lane-min is a distinct real point's distance => tau1 >= true r32.
    {
        float rmin = INFINITY;
        for (int pb = 0; pb < npar; pb += 64) {
            int myA = 0, myE = 0;
            if (pb + lane < npar) {
                const int par = (int)s_pl[wid][pb + lane];
                myA = (int)s_poff[par];
                myE = (int)s_poff[par + 1];
            }
            const int nb = imin(64, npar - pb);
            for (int ci = 0; ci < nb; ++ci) {
                const int a = __shfl(myA, ci);
                const int e = __shfl(myE, ci);
                for (int j = a + lane; j < e; j += 64)
                    rmin = fminf(rmin, dist2f(p4[j], qx, qy, qz));
            }
        }
        v = rmin;
#pragma unroll
        for (int k2 = 2; k2 <= 64; k2 <<= 1) {
#pragma unroll
            for (int jj = k2 >> 1; jj >= 1; jj >>= 1) {
                const float o     = __shfl_xor(v, jj);
                const bool  up    = ((lane & k2) == 0);
                const bool  lower = ((lane & jj) == 0);
                v = (lower == up) ? fminf(v, o) : fmaxf(v, o);
            }
        }
    }
    const float tau1r = __shfl(v, 31);
    const float taum  = fminf(tau1r, tau0r) * 1.00002f + 1e-6f;

    // ---- refilter parents at taum, in-place stream compaction ----
    // (reads of round r at pb+lane; writes at < pb+64: safe)
    {
        int npar2 = 0;
        for (int pb = 0; pb < npar; pb += 64) {
            uint16_t pc = 0; bool pp = false;
            if (pb + lane < npar) {
                pc = s_pl[wid][pb + lane];
                const float ddx = fmaxf(fmaxf(s_blo[pc][0] - qx, qx - s_bhi[pc][0]), 0.0f);
                const float ddy = fmaxf(fmaxf(s_blo[pc][1] - qy, qy - s_bhi[pc][1]), 0.0f);
                const float ddz = fmaxf(fmaxf(s_blo[pc][2] - qz, qz - s_bhi[pc][2]), 0.0f);
                pp = (fmaf(ddx, ddx, fmaf(ddy, ddy, ddz * ddz)) <= taum);
            }
            const unsigned long long m = __ballot(pp);
            if (pp) s_pl[wid][npar2 + (int)__popcll(m & lt)] = pc;
            npar2 += (int)__popcll(m);
        }
        npar = npar2;
    }

    // ---- cell filter at taum: 8 parents/round, geometric child boxes ----
    bool slow = false;
    int ncell = 0;
    for (int pi = 0; pi < npar; pi += 8) {
        const int g   = pi + (lane >> 3);
        const int par = (g < npar) ? (int)s_pl[wid][g] : -1;
        const int cell = (par >= 0) ? (par * 8 + (lane & 7)) : 0;
        int n = 0;
        float dmc = 1e30f;
        if (par >= 0) {
            n = (int)s_off[cell + 1] - (int)s_off[cell];
            dmc = cell_dmin2(cell, qx, qy, qz);
        }
        const bool pass = (n > 0) && (dmc <= taum);
        const unsigned long long m = __ballot(pass);
        if (pass) {
            const int pos = ncell + (int)__popcll(m & lt);
            if (pos < CCAP) s_cell[wid][pos] = (uint16_t)cell;
        }
        ncell += (int)__popcll(m);
    }
    slow = (ncell > CCAP);

    // ---- collect at taum (exact count; one sweep over cells) ----
    int M = 0;
    if (!slow) {
        for (int ci = 0; ci < ncell; ++ci) {
            const int cell = (int)s_cell[wid][ci];
            const int a = (int)s_off[cell];
            const int e = (int)s_off[cell + 1];
            for (int rr = a; rr < e; rr += 64) {
                const int j = rr + lane;
                const bool hit = (j < e) && (dist2f(p4[j], qx, qy, qz) <= taum);
                const unsigned long long m = __ballot(hit);
                if (hit) {
                    const int pp = M + (int)__popcll(m & lt);
                    if (pp < MCAP) s_cand[wid][pp] = (uint16_t)j;
                }
                M += (int)__popcll(m);
            }
        }
        slow = (M > MCAP);
        // M >= 32: >=32 points with d<=tau1m lie in taum-passing parents/cells
    }

    // =================== FAST PATH: fp64 re-rank of <=128 ===================
    if (!slow) {
        const double axd = (double)qx, ayd = (double)qy, azd = (double)qz;
        const int i0 = (2 * lane     < M) ? (int)s_cand[wid][2 * lane]     : -1;
        const int i1 = (2 * lane + 1 < M) ? (int)s_cand[wid][2 * lane + 1] : -1;
        float f0 = INFINITY, f1 = INFINITY;
        if (i0 >= 0) {
            const f32x4 p = p4[i0];
            const double dx = (double)p.x - axd, dy = (double)p.y - ayd, dz = (double)p.z - azd;
            f0 = (float)(dx * dx + dy * dy + dz * dz);
        }
        if (i1 >= 0) {
            const f32x4 p = p4[i1];
            const double dx = (double)p.x - axd, dy = (double)p.y - ayd, dz = (double)p.z - azd;
            f1 = (float)(dx * dx + dy * dy + dz * dz);
        }
        int v0 = __float_as_int(f0);
        int v1 = __float_as_int(f1);
#pragma unroll
        for (int k2 = 2; k2 <= 128; k2 <<= 1) {
            const bool up = ((lane & (k2 >> 1)) == 0);
#pragma unroll
            for (int j = k2 >> 1; j >= 2; j >>= 1) {
                const int  xo    = j >> 1;
                const bool lower = ((lane & xo) == 0);
                const int o0 = __shfl_xor(v0, xo);
                const int o1 = __shfl_xor(v1, xo);
                v0 = (lower == up) ? imin(v0, o0) : imax(v0, o0);
                v1 = (lower == up) ? imin(v1, o1) : imax(v1, o1);
            }
            const int mn = imin(v0, v1), mx = imax(v0, v1);
            v0 = up ? mn : mx;
            v1 = up ? mx : mn;
        }
        const int tau32 = __shfl(v1, 15);   // rank-31 key (32nd smallest)

        const bool a0 = (i0 >= 0) && (__float_as_int(f0) <= tau32);
        const bool a1 = (i1 >= 0) && (__float_as_int(f1) <= tau32);
        const unsigned long long b0 = __ballot(a0);
        const unsigned long long b1 = __ballot(a1);
        const int cb2 = (int)__popcll(b0 & lt) + (int)__popcll(b1 & lt);
        const int p0 = cb2;
        const int p1 = cb2 + (a0 ? 1 : 0);
        if (a0 && p0 < KSEL) { s_wd2[wid][p0] = f0; s_widx[wid][p0] = (uint16_t)i0; }
        if (a1 && p1 < KSEL) { s_wd2[wid][p1] = f1; s_widx[wid][p1] = (uint16_t)i1; }
    }

    // ============ SLOW PATH (astronomical): streaming u64 top-64 ============
    if (slow) {
        u64 L = INFKEY;
#pragma unroll 1
        for (int r = 0; r < 8; ++r) {
            const int c = r * 64 + lane;
            const float ddx = fmaxf(fmaxf(s_blo[c][0] - qx, qx - s_bhi[c][0]), 0.0f);
            const float ddy = fmaxf(fmaxf(s_blo[c][1] - qy, qy - s_bhi[c][1]), 0.0f);
            const float ddz = fmaxf(fmaxf(s_blo[c][2] - qz, qz - s_bhi[c][2]), 0.0f);
            const float dmin = fmaf(ddx, ddx, fmaf(ddy, ddy, ddz * ddz));
            unsigned long long pm = __ballot(dmin <= tau0m);
            while (pm) {
                const int pl = __ffsll(pm) - 1; pm &= pm - 1;
                const int par = r * 64 + pl;
                const int a = (int)s_off[par * 8];
                const int e = (int)s_off[par * 8 + 8];   // children contiguous
                for (int rr = a; rr < e; rr += 64) {
                    const int j = rr + lane;
                    u64 b = INFKEY;
                    if (j < e) {
                        const float d2 = dist2f(p4[j], qx, qy, qz);
                        b = (((u64)__float_as_uint(d2)) << 16) | (u64)j;
                    }
                    const u64 worst = __shfl(L, 63);
                    if (!__any(b < worst)) continue;
#pragma unroll
                    for (int k2 = 2; k2 <= 64; k2 <<= 1) {
#pragma unroll
                        for (int jj = k2 >> 1; jj >= 1; jj >>= 1) {
                            const u64  o     = __shfl_xor(b, jj);
                            const bool up    = ((lane & k2) == 0);
                            const bool lower = ((lane & jj) == 0);
                            b = (lower == up) ? umin64(b, o) : umax64(b, o);
                        }
                    }
                    L = umin64(L, __shfl_xor(b, 63));
#pragma unroll
                    for (int jj = 32; jj >= 1; jj >>= 1) {
                        const u64 o = __shfl_xor(L, jj);
                        L = ((lane & jj) == 0) ? umin64(L, o) : umax64(L, o);
                    }
                }
            }
        }
        const double axd = (double)qx, ayd = (double)qy, azd = (double)qz;
        const bool valid = (L != INFKEY);
        const int  slot  = (int)(L & 0xFFFFull);
        float fd2 = INFINITY;
        if (valid) {
            const f32x4 p = p4[slot];
            const double dx = (double)p.x - axd;
            const double dy = (double)p.y - ayd;
            const double dz = (double)p.z - azd;
            fd2 = (float)(dx * dx + dy * dy + dz * dz);
        }
        u64 k2v = (((u64)__float_as_uint(fd2)) << 16)
                | (u64)(valid ? slot : 0xFFFF);
#pragma unroll
        for (int k2 = 2; k2 <= 64; k2 <<= 1) {
#pragma unroll
            for (int jj = k2 >> 1; jj >= 1; jj >>= 1) {
                const u64  o     = __shfl_xor(k2v, jj);
                const bool up    = ((lane & k2) == 0);
                const bool lower = ((lane & jj) == 0);
                k2v = (lower == up) ? umin64(k2v, o) : umax64(k2v, o);
            }
        }
        if (lane < KSEL) {
            s_wd2[wid][lane]  = __uint_as_float((uint32_t)(k2v >> 16));
            s_widx[wid][lane] = (uint16_t)(k2v & 0xFFFFull);
        }
    }

    // ---- common: weights (slot -> orig, normalize once) ----
    {
        float w = 0.0f;
        int orig = 0;
        if (lane < KSEL) {
            const int slot = (int)s_widx[wid][lane];
            orig = __float_as_int(p4[slot].w);
            w = __builtin_amdgcn_rcpf(fmaxf(s_wd2[wid][lane], 1e-16f));
        }
        float wsum = w;
#pragma unroll
        for (int d = 1; d < 32; d <<= 1) wsum += __shfl_xor(wsum, d);
        if (lane < KSEL) {
            s_wd2[wid][lane]  = w * __builtin_amdgcn_rcpf(wsum);
            s_widx[wid][lane] = (uint16_t)orig;
        }
    }

    // ---- feature gather + weighted average (writes to ORIGINAL slot) ----
    f32x2 acc = (f32x2){0.0f, 0.0f};
#pragma unroll 8
    for (int kk = 0; kk < KSEL; ++kk) {
        const float w    = s_wd2[wid][kk];
        const int   orig = (int)s_widx[wid][kk];
        const f32x2 r2 = *(const f32x2*)(x + (size_t)orig * FDIM + 2 * lane);
        acc.x = fmaf(w, r2.x, acc.x);
        acc.y = fmaf(w, r2.y, acc.y);
    }
    *(f32x2*)(out + (size_t)sq * FDIM + 2 * lane) = acc;
}

// ---------------------------------------------------------------------------
// Fallback: verified round-2 brute-force kernel (used if ws too small)
// ---------------------------------------------------------------------------
#define CHUNK  1024
#define NCHUNK (NL / CHUNK)
#define QPW    4
#define NWAVES 8
#define BLOCK  (NWAVES * 64)
#define QPB    (NWAVES * QPW)
#define BUFCAP 128

__device__ __forceinline__ f32x2 pk_fma_lo(f32x2 s0, f32x2 s1, f32x2 s2) {
    f32x2 d;
    asm("v_pk_fma_f32 %0, %1, %2, %3 op_sel:[0,0,0] op_sel_hi:[1,0,1]"
        : "=v"(d) : "v"(s0), "v"(s1), "v"(s2));
    return d;
}
__device__ __forceinline__ f32x2 pk_fma_hi(f32x2 s0, f32x2 s1, f32x2 s2) {
    f32x2 d;
    asm("v_pk_fma_f32 %0, %1, %2, %3 op_sel:[0,1,0] op_sel_hi:[1,1,1]"
        : "=v"(d) : "v"(s0), "v"(s1), "v"(s2));
    return d;
}

__global__ __launch_bounds__(BLOCK, 8)
void knn_interp_kernel(const float* __restrict__ x,
                       const float* __restrict__ pos_l,
                       const float* __restrict__ pos_h,
                       float* __restrict__ out)
{
    __shared__ f32x2    s_x[CHUNK/2], s_y[CHUNK/2], s_z[CHUNK/2], s_w[CHUNK/2];
    __shared__ uint16_t s_idx[QPB][BUFCAP];
    __shared__ uint32_t s_cnt[QPB];
    __shared__ float    s_wd2[QPB][KSEL];
    __shared__ uint16_t s_widx[QPB][KSEL];

    const int tid   = threadIdx.x;
    const int lane  = tid & 63;
    const int wid   = tid >> 6;
    const int qbase = blockIdx.x * QPB + wid * QPW;

    f32x2 hxq[QPW/2], hyq[QPW/2], hzq[QPW/2];
#pragma unroll
    for (int j = 0; j < QPW/2; ++j) {
        const float a0x = pos_h[(size_t)(qbase + 2*j    ) * 3 + 0];
        const float a0y = pos_h[(size_t)(qbase + 2*j    ) * 3 + 1];
        const float a0z = pos_h[(size_t)(qbase + 2*j    ) * 3 + 2];
        const float a1x = pos_h[(size_t)(qbase + 2*j + 1) * 3 + 0];
        const float a1y = pos_h[(size_t)(qbase + 2*j + 1) * 3 + 1];
        const float a1z = pos_h[(size_t)(qbase + 2*j + 1) * 3 + 2];
        hxq[j] = (f32x2){-2.0f * a0x, -2.0f * a1x};
        hyq[j] = (f32x2){-2.0f * a0y, -2.0f * a1y};
        hzq[j] = (f32x2){-2.0f * a0z, -2.0f * a1z};
    }
    f32x2 rminp[QPW];
#pragma unroll
    for (int q = 0; q < QPW; ++q) rminp[q] = (f32x2){INFINITY, INFINITY};

    for (int c = 0; c < NCHUNK; ++c) {
        __syncthreads();
        for (int i = tid; i < CHUNK/2; i += BLOCK) {
            const float* p = pos_l + (size_t)(c * CHUNK + 2 * i) * 3;
            const f32x2 A = *(const f32x2*)(p + 0);
            const f32x2 B = *(const f32x2*)(p + 2);
            const f32x2 C = *(const f32x2*)(p + 4);
            s_x[i] = (f32x2){A.x, B.y};
            s_y[i] = (f32x2){A.y, C.x};
            s_z[i] = (f32x2){B.x, C.y};
            s_w[i] = (f32x2){fmaf(A.x, A.x, fmaf(A.y, A.y, B.x * B.x)),
                             fmaf(B.y, B.y, fmaf(C.x, C.x, C.y * C.y))};
        }
        __syncthreads();
#pragma unroll
        for (int i = 0; i < CHUNK/128; ++i) {
            const int pi = i * 64 + lane;
            const f32x2 xp = s_x[pi], yp = s_y[pi], zp = s_z[pi], wp = s_w[pi];
#pragma unroll
            for (int j = 0; j < QPW/2; ++j) {
                f32x2 t0 = pk_fma_lo(xp, hxq[j], wp);
                t0 = pk_fma_lo(yp, hyq[j], t0);
                t0 = pk_fma_lo(zp, hzq[j], t0);
                rminp[2*j].x = fminf(rminp[2*j].x, t0.x);
                rminp[2*j].y = fminf(rminp[2*j].y, t0.y);
                f32x2 t1 = pk_fma_hi(xp, hxq[j], wp);
                t1 = pk_fma_hi(yp, hyq[j], t1);
                t1 = pk_fma_hi(zp, hzq[j], t1);
                rminp[2*j+1].x = fminf(rminp[2*j+1].x, t1.x);
                rminp[2*j+1].y = fminf(rminp[2*j+1].y, t1.y);
            }
        }
    }
    float tau_acc[QPW];
#pragma unroll
    for (int q = 0; q < QPW; ++q) {
        float v = fminf(rminp[q].x, rminp[q].y);
#pragma unroll
        for (int k = 2; k <= 64; k <<= 1) {
#pragma unroll
            for (int jj = k >> 1; jj >= 1; jj >>= 1) {
                const float o     = __shfl_xor(v, jj);
                const bool  up    = ((lane & k) == 0);
                const bool  lower = ((lane & jj) == 0);
                v = (lower == up) ? fminf(v, o) : fmaxf(v, o);
            }
        }
        tau_acc[q] = __shfl(v, 31) + 1e-4f;
    }
    if (tid < QPB) s_cnt[tid] = 0;
    for (int c = 0; c < NCHUNK; ++c) {
        __syncthreads();
        for (int i = tid; i < CHUNK/2; i += BLOCK) {
            const float* p = pos_l + (size_t)(c * CHUNK + 2 * i) * 3;
            const f32x2 A = *(const f32x2*)(p + 0);
            const f32x2 B = *(const f32x2*)(p + 2);
            const f32x2 C = *(const f32x2*)(p + 4);
            s_x[i] = (f32x2){A.x, B.y};
            s_y[i] = (f32x2){A.y, C.x};
            s_z[i] = (f32x2){B.x, C.y};
            s_w[i] = (f32x2){fmaf(A.x, A.x, fmaf(A.y, A.y, B.x * B.x)),
                             fmaf(B.y, B.y, fmaf(C.x, C.x, C.y * C.y))};
        }
        __syncthreads();
#pragma unroll 2
        for (int i = 0; i < CHUNK/128; ++i) {
            const int pi = i * 64 + lane;
            const f32x2 xp = s_x[pi], yp = s_y[pi], zp = s_z[pi], wp = s_w[pi];
            const int g0 = c * CHUNK + 2 * pi;
#pragma unroll
            for (int j = 0; j < QPW/2; ++j) {
                f32x2 t0 = pk_fma_lo(xp, hxq[j], wp);
                t0 = pk_fma_lo(yp, hyq[j], t0);
                t0 = pk_fma_lo(zp, hzq[j], t0);
                f32x2 t1 = pk_fma_hi(xp, hxq[j], wp);
                t1 = pk_fma_hi(yp, hyq[j], t1);
                t1 = pk_fma_hi(zp, hzq[j], t1);
                const int q0 = wid * QPW + 2*j;
                if (__any(fminf(t0.x, t0.y) <= tau_acc[2*j])) {
                    if (t0.x <= tau_acc[2*j]) {
                        const uint32_t p0 = atomicAdd(&s_cnt[q0], 1u);
                        if (p0 < BUFCAP) s_idx[q0][p0] = (uint16_t)g0;
                    }
                    if (t0.y <= tau_acc[2*j]) {
                        const uint32_t p0 = atomicAdd(&s_cnt[q0], 1u);
                        if (p0 < BUFCAP) s_idx[q0][p0] = (uint16_t)(g0 + 1);
                    }
                }
                if (__any(fminf(t1.x, t1.y) <= tau_acc[2*j+1])) {
                    if (t1.x <= tau_acc[2*j+1]) {
                        const uint32_t p0 = atomicAdd(&s_cnt[q0 + 1], 1u);
                        if (p0 < BUFCAP) s_idx[q0 + 1][p0] = (uint16_t)g0;
                    }
                    if (t1.y <= tau_acc[2*j+1]) {
                        const uint32_t p0 = atomicAdd(&s_cnt[q0 + 1], 1u);
                        if (p0 < BUFCAP) s_idx[q0 + 1][p0] = (uint16_t)(g0 + 1);
                    }
                }
            }
        }
    }
#pragma unroll 1
    for (int q = 0; q < QPW; ++q) {
        const int qq = wid * QPW + q;
        uint32_t M = s_cnt[qq];
        if (M > BUFCAP) M = BUFCAP;
        const double axd = (double)pos_h[(size_t)(qbase + q) * 3 + 0];
        const double ayd = (double)pos_h[(size_t)(qbase + q) * 3 + 1];
        const double azd = (double)pos_h[(size_t)(qbase + q) * 3 + 2];
        const int i0 = ((uint32_t)(2 * lane)     < M) ? (int)s_idx[qq][2 * lane]     : -1;
        const int i1 = ((uint32_t)(2 * lane + 1) < M) ? (int)s_idx[qq][2 * lane + 1] : -1;
        float f0 = INFINITY, f1 = INFINITY;
        if (i0 >= 0) {
            const double dx = (double)pos_l[i0 * 3 + 0] - axd;
            const double dy = (double)pos_l[i0 * 3 + 1] - ayd;
            const double dz = (double)pos_l[i0 * 3 + 2] - azd;
            f0 = (float)(dx * dx + dy * dy + dz * dz);
        }
        if (i1 >= 0) {
            const double dx = (double)pos_l[i1 * 3 + 0] - axd;
            const double dy = (double)pos_l[i1 * 3 + 1] - ayd;
            const double dz = (double)pos_l[i1 * 3 + 2] - azd;
            f1 = (float)(dx * dx + dy * dy + dz * dz);
        }
        int v0 = __float_as_int(f0);
        int v1 = __float_as_int(f1);
#pragma unroll
        for (int k = 2; k <= 128; k <<= 1) {
            const bool up = ((lane & (k >> 1)) == 0);
#pragma unroll
            for (int j = k >> 1; j >= 2; j >>= 1) {
                const int  xo    = j >> 1;
                const bool lower = ((lane & xo) == 0);
                const int o0 = __shfl_xor(v0, xo);
                const int o1 = __shfl_xor(v1, xo);
                v0 = (lower == up) ? imin(v0, o0) : imax(v0, o0);
                v1 = (lower == up) ? imin(v1, o1) : imax(v1, o1);
            }
            const int mn = imin(v0, v1), mx = imax(v0, v1);
            v0 = up ? mn : mx;
            v1 = up ? mx : mn;
        }
        const int tau32 = __shfl(v1, 15);
        const bool a0 = (i0 >= 0) && (__float_as_int(f0) <= tau32);
        const bool a1 = (i1 >= 0) && (__float_as_int(f1) <= tau32);
        const unsigned long long b0 = __ballot(a0);
        const unsigned long long b1 = __ballot(a1);
        const unsigned long long mb = (lane == 63) ? 0x7FFFFFFFFFFFFFFFull
                                                   : ((1ull << (lane + 1)) - 1ull) >> 1;
        const int base = __popcll(b0 & mb) + __popcll(b1 & mb);
        const int p0 = base;
        const int p1 = base + (a0 ? 1 : 0);
        if (a0 && p0 < KSEL) { s_wd2[qq][p0] = f0; s_widx[qq][p0] = (uint16_t)i0; }
        if (a1 && p1 < KSEL) { s_wd2[qq][p1] = f1; s_widx[qq][p1] = (uint16_t)i1; }
    }
#pragma unroll 1
    for (int q = 0; q < QPW; ++q) {
        const int qq = wid * QPW + q;
        const int gq = qbase + q;
        f32x2 acc = (f32x2){0.0f, 0.0f};
        float wsum = 0.0f;
#pragma unroll 8
        for (int kk = 0; kk < KSEL; ++kk) {
            const float d2 = s_wd2[qq][kk];
            const float w  = __builtin_amdgcn_rcpf(fmaxf(d2, 1e-16f));
            const int  idx = (int)s_widx[qq][kk];
            const f32x2 r2 = *(const f32x2*)(x + (size_t)idx * FDIM + 2 * lane);
            acc.x = fmaf(w, r2.x, acc.x);
            acc.y = fmaf(w, r2.y, acc.y);
            wsum += w;
        }
        const float invw = __builtin_amdgcn_rcpf(wsum);
        out[(size_t)gq * FDIM + 2 * lane]     = acc.x * invw;
        out[(size_t)gq * FDIM + 2 * lane + 1] = acc.y * invw;
    }
}

// ---------------------------------------------------------------------------
extern "C" void kernel_launch(void* const* d_in, const int* in_sizes, int n_in,
                              void* d_out, int out_size, void* d_ws, size_t ws_size,
                              hipStream_t stream) {
    const float* x     = (const float*)d_in[0];
    const float* pos_l = (const float*)d_in[1];
    const float* pos_h = (const float*)d_in[2];
    float* out = (float*)d_out;

    if (d_ws != nullptr && ws_size >= (size_t)WS_BYTES) {
        float* ws = (float*)d_ws;
        hipLaunchKernelGGL(k_init,    dim3(16),  dim3(256),  0, stream, ws);
        hipLaunchKernelGGL(k_count,   dim3(32),  dim3(256),  0, stream, pos_l, ws);
        hipLaunchKernelGGL(k_scan,    dim3(1),   dim3(1024), 0, stream, ws);
        hipLaunchKernelGGL(k_scatter, dim3(32),  dim3(256),  0, stream, pos_l, ws);
        hipLaunchKernelGGL(q_init,    dim3(16),  dim3(256),  0, stream, ws);
        hipLaunchKernelGGL(q_count,   dim3(128), dim3(256),  0, stream, pos_h, ws);
        hipLaunchKernelGGL(q_scan,    dim3(1),   dim3(1024), 0, stream, ws);
        hipLaunchKernelGGL(q_scatter, dim3(128), dim3(256),  0, stream, pos_h, ws);
        hipLaunchKernelGGL(query_kernel, dim3(NH / QBLK), dim3(512), 0, stream,
                           x, pos_h, ws, out);
    } else {
        hipLaunchKernelGGL(knn_interp_kernel, dim3(NH / QPB), dim3(BLOCK), 0, stream,
                           x, pos_l, pos_h, out);
    }
}